// Round 11
// baseline (1483.201 us; speedup 1.0000x reference)
//
#include <hip/hip_runtime.h>
#include <math.h>

#define NN 50000      // nodes
#define GG 100        // graphs
#define NPGc 500      // nodes per graph
#define HH 256        // hidden
#define IND 128       // input dim

typedef __attribute__((ext_vector_type(8))) short short8v;  // 8 bf16
typedef __attribute__((ext_vector_type(4))) float f32x4;

__device__ __forceinline__ ushort f2bf(float f) {
    union { float f; unsigned u; } v; v.f = f;
    unsigned r = (v.u + 0x7fffu + ((v.u >> 16) & 1u)) >> 16;  // RNE
    return (ushort)r;
}
__device__ __forceinline__ float bf2f(ushort h) {
    union { unsigned u; float f; } v; v.u = ((unsigned)h) << 16;
    return v.f;
}

// LDS ushort-index swizzle (read side). Sources are PRE-swizzled so that a
// LINEAR global_load_lds copy lands data exactly where swz-reads expect it
// (both-sides-or-neither rule, m173/m201).
__device__ __forceinline__ int swz(int row, int kidx) { return kidx ^ ((row & 7) << 3); }

// async global->LDS, 16B per lane. lds ptr MUST be wave-uniform.
__device__ __forceinline__ void llds16(const ushort* g, ushort* l)
{
    __builtin_amdgcn_global_load_lds(
        (const __attribute__((address_space(1))) void*)g,
        (__attribute__((address_space(3))) void*)l, 16, 0, 0);
}

// ---------------------------------------------------------------------------
// Weight transpose+convert: src [K][N] f32 -> dst [N][K] bf16, PRE-SWIZZLED
// (granule XOR within each 64-k tile) for linear DMA staging.
// ---------------------------------------------------------------------------
__global__ void wcvt(const float* __restrict__ src, ushort* __restrict__ dst, int K, int N)
{
    int i = blockIdx.x * 256 + threadIdx.x;
    if (i < K * N) {
        int n = i / K, k = i % K;
        dst[(size_t)n * K + (k ^ ((n & 7) << 3))] = f2bf(src[(size_t)k * N + n]);
    }
}

// ---------------------------------------------------------------------------
// bf16 MFMA GEMM: C[M x 256] = A[M x K](f32, cvt on stage) @ Wt[N][K](bf16,
// pre-swizzled; staged via global_load_lds). tile 128x128, BK=64, 4 waves.
// mode 0: C=f32(+bias). mode 1: gate epilogue. mode 2: Cbf=bf16 linear(+bias).
// ---------------------------------------------------------------------------
__global__ __launch_bounds__(256)
void gemm_mfma(const float* __restrict__ A, const float* __restrict__ A2,
               const ushort* __restrict__ Wt, const float* __restrict__ bias,
               float* __restrict__ C, ushort* __restrict__ Cbf,
               int M, int K, int lda, int mode,
               const float* __restrict__ hn, const float* __restrict__ fn,
               const float* __restrict__ prev)
{
    __shared__ ushort As[128][64];
    __shared__ ushort Bs[128][64];
    const int tid = threadIdx.x;
    const int lane = tid & 63;
    const int w = tid >> 6;
    const int wr = (w >> 1) * 64, wc = (w & 1) * 64;
    const int row0 = blockIdx.x * 128, col0 = blockIdx.y * 128;
    const int lr = lane & 15, lk = (lane >> 4) * 8;
    f32x4 acc[4][4] = {};

    for (int k0 = 0; k0 < K; k0 += 64) {
        __syncthreads();
        #pragma unroll
        for (int it = 0; it < 4; ++it) {           // stage A: 128x64, f32->bf16
            int c = it * 256 + tid;
            int row = c >> 3, col = (c & 7) * 8;
            int gr = row0 + row; if (gr > M - 1) gr = M - 1;
            const float* Ap = A; int kk = k0 + col;
            if (A2 != nullptr && kk >= 256) { Ap = A2; kk -= 256; }
            const float* s = &Ap[(size_t)gr * lda + kk];
            float4 v0 = *(const float4*)s;
            float4 v1 = *(const float4*)(s + 4);
            union { ushort u[8]; int4 q; } pk;
            pk.u[0] = f2bf(v0.x); pk.u[1] = f2bf(v0.y); pk.u[2] = f2bf(v0.z); pk.u[3] = f2bf(v0.w);
            pk.u[4] = f2bf(v1.x); pk.u[5] = f2bf(v1.y); pk.u[6] = f2bf(v1.z); pk.u[7] = f2bf(v1.w);
            *(int4*)&As[row][swz(row, col)] = pk.q;
        }
        // stage B via DMA: 16KB linear (Wt pre-swizzled). chunk = 8 rows.
        #pragma unroll
        for (int i = 0; i < 4; ++i) {
            int ch = w * 4 + i;                    // wave-uniform
            int brow = ch * 8 + (lane >> 3);
            int gq = lane & 7;
            llds16(&Wt[(size_t)(col0 + brow) * K + k0 + gq * 8],
                   &Bs[0][0] + ch * 512);
        }
        __syncthreads();
        #pragma unroll
        for (int ks = 0; ks < 2; ++ks) {
            short8v av[4], bv[4];
            #pragma unroll
            for (int m = 0; m < 4; ++m) {
                int rr = wr + m * 16 + lr;
                av[m] = *(const short8v*)&As[rr][swz(rr, ks * 32 + lk)];
            }
            #pragma unroll
            for (int n = 0; n < 4; ++n) {
                int rr = wc + n * 16 + lr;
                bv[n] = *(const short8v*)&Bs[rr][swz(rr, ks * 32 + lk)];
            }
            #pragma unroll
            for (int m = 0; m < 4; ++m)
                #pragma unroll
                for (int n = 0; n < 4; ++n)
                    acc[m][n] = __builtin_amdgcn_mfma_f32_16x16x32_bf16(av[m], bv[n], acc[m][n], 0, 0, 0);
        }
    }
    const int fr = (lane >> 4) * 4;
    if (mode == 0) {
        #pragma unroll
        for (int n = 0; n < 4; ++n) {
            int col = col0 + wc + n * 16 + lr;
            float bb = bias ? bias[col] : 0.f;
            #pragma unroll
            for (int m = 0; m < 4; ++m) {
                int rbase = row0 + wr + m * 16 + fr;
                #pragma unroll
                for (int r = 0; r < 4; ++r) {
                    int row = rbase + r;
                    if (row < M) C[(size_t)row * HH + col] = acc[m][n][r] + bb;
                }
            }
        }
    } else if (mode == 2) {
        #pragma unroll
        for (int n = 0; n < 4; ++n) {
            int col = col0 + wc + n * 16 + lr;
            float bb = bias ? bias[col] : 0.f;
            #pragma unroll
            for (int m = 0; m < 4; ++m) {
                int rbase = row0 + wr + m * 16 + fr;
                #pragma unroll
                for (int r = 0; r < 4; ++r) {
                    int row = rbase + r;
                    if (row < M) Cbf[(size_t)row * HH + col] = f2bf(acc[m][n][r] + bb);
                }
            }
        }
    } else {
        #pragma unroll
        for (int n = 0; n < 4; ++n) {
            int col = col0 + wc + n * 16 + lr;
            float gb = bias[col];
            #pragma unroll
            for (int m = 0; m < 4; ++m) {
                int rbase = row0 + wr + m * 16 + fr;
                #pragma unroll
                for (int r = 0; r < 4; ++r) {
                    int row = rbase + r;
                    if (row < M) {
                        size_t o = (size_t)row * HH + col;
                        float z = acc[m][n][r] + gb;
                        float s = 1.f / (1.f + expf(-z));
                        C[o] = s * hn[o] + (1.f - s) * fn[o] + prev[o];
                    }
                }
            }
        }
    }
}

// ---------------------------------------------------------------------------
// Row L2-normalize, emit bf16 hi/lo split PRE-SWIZZLED for DMA staging
// ---------------------------------------------------------------------------
__global__ __launch_bounds__(256)
void row_norm_hl(const float* __restrict__ h, ushort* __restrict__ xh, ushort* __restrict__ xl)
{
    int n = blockIdx.x, c = threadIdx.x;
    float v = h[(size_t)n * HH + c];
    __shared__ float red[256];
    red[c] = v * v;
    __syncthreads();
    for (int s = 128; s > 0; s >>= 1) {
        if (c < s) red[c] += red[c + s];
        __syncthreads();
    }
    float norm = sqrtf(red[0]);
    float xn = v / (norm + 1e-12f);
    ushort hi = f2bf(xn);
    int cs = c ^ ((n & 7) << 3);
    xh[(size_t)n * HH + cs] = hi;
    xl[(size_t)n * HH + cs] = f2bf(xn - bf2f(hi));
}

// ---------------------------------------------------------------------------
// top-3 helpers (exact top_k tie-breaking: value desc, index asc)
// ---------------------------------------------------------------------------
__device__ __forceinline__ bool tk_better(float va, int ia, float vb, int ib)
{
    return (va > vb) || (va == vb && ia < ib);
}

__device__ __forceinline__ void ins3(float v, int i,
                                     float& a0, int& b0, float& a1, int& b1,
                                     float& a2, int& b2)
{
    if (tk_better(v, i, a0, b0))      { a2 = a1; b2 = b1; a1 = a0; b1 = b0; a0 = v; b0 = i; }
    else if (tk_better(v, i, a1, b1)) { a2 = a1; b2 = b1; a1 = v;  b1 = i; }
    else if (tk_better(v, i, a2, b2)) { a2 = v;  b2 = i; }
}

__device__ __forceinline__ void merge3(float& v0, float& v1, float& v2,
                                       int& i0, int& i1, int& i2, int off)
{
    float w0 = __shfl_xor(v0, off), w1 = __shfl_xor(v1, off), w2 = __shfl_xor(v2, off);
    int   j0 = __shfl_xor(i0, off), j1 = __shfl_xor(i1, off), j2 = __shfl_xor(i2, off);
    float avv[3] = { v0, v1, v2 }, bvv[3] = { w0, w1, w2 };
    int   aii[3] = { i0, i1, i2 }, bii[3] = { j0, j1, j2 };
    float rv[3]; int ri[3];
    int p = 0, q = 0;
    #pragma unroll
    for (int t = 0; t < 3; ++t) {
        bool takeA = tk_better(avv[p], aii[p], bvv[q], bii[q]);
        rv[t] = takeA ? avv[p] : bvv[q];
        ri[t] = takeA ? aii[p] : bii[q];
        if (takeA) ++p; else ++q;
    }
    v0 = rv[0]; v1 = rv[1]; v2 = rv[2];
    i0 = ri[0]; i1 = ri[1]; i2 = ri[2];
}

// ---------------------------------------------------------------------------
// simtopk v6: all-DMA staging (global_load_lds width 16, pre-swizzled source,
// linear LDS, swz reads -> conflict-free). Block = 64 rows of one graph,
// 4 waves x 16 rows; BK=64; 4 col-tiles of 128. LDS 48KB.
// XCD-swizzled grid: 8 row-blocks of a graph share one XCD residue.
// ---------------------------------------------------------------------------
__global__ __launch_bounds__(256)
void simtopk(const ushort* __restrict__ xnh, const ushort* __restrict__ xnl,
             int* __restrict__ fsrc)
{
    __shared__ ushort AshL[64][64], AslL[64][64];   // 16 KB
    __shared__ ushort BshL[128][64], BslL[128][64]; // 32 KB
    const int bid = blockIdx.x;
    const int xcd = bid & 7;
    const int rb  = (bid >> 3) & 7;
    const int g   = (bid >> 6) * 8 + xcd;
    if (g >= GG) return;
    const int row0 = rb * 64;
    const int tid  = threadIdx.x;
    const int lane = tid & 63;
    const int w    = tid >> 6;
    const int lr   = lane & 15;
    const int hi4  = lane >> 4;
    const int lk   = hi4 * 8;
    const size_t base = (size_t)g * NPGc * HH;
    const int r8 = lane >> 3, gq = lane & 7;

    float tv0[4], tv1[4], tv2[4];
    int   ti0[4], ti1[4], ti2[4];
    #pragma unroll
    for (int r = 0; r < 4; ++r) {
        tv0[r] = tv1[r] = tv2[r] = -2.f;
        ti0[r] = ti1[r] = ti2[r] = 0x7fffffff;
    }

    for (int ct = 0; ct < 4; ++ct) {
        const int col0 = ct * 128;
        f32x4 acc[8] = {};
        for (int k0 = 0; k0 < HH; k0 += 64) {
            __syncthreads();
            // 48 DMA chunks (8 Ash, 8 Asl, 16 Bsh, 16 Bsl); wave w: 12 chunks
            #pragma unroll
            for (int i = 0; i < 12; ++i) {
                int ch = w * 12 + i;               // wave-uniform
                if (ch < 8) {
                    int row = ch * 8 + r8;
                    int gr = row0 + row; if (gr > NPGc - 1) gr = NPGc - 1;
                    llds16(xnh + base + (size_t)gr * HH + k0 + gq * 8,
                           &AshL[0][0] + ch * 512);
                } else if (ch < 16) {
                    int row = (ch - 8) * 8 + r8;
                    int gr = row0 + row; if (gr > NPGc - 1) gr = NPGc - 1;
                    llds16(xnl + base + (size_t)gr * HH + k0 + gq * 8,
                           &AslL[0][0] + (ch - 8) * 512);
                } else if (ch < 32) {
                    int row = (ch - 16) * 8 + r8;
                    int gc = col0 + row; if (gc > NPGc - 1) gc = NPGc - 1;
                    llds16(xnh + base + (size_t)gc * HH + k0 + gq * 8,
                           &BshL[0][0] + (ch - 16) * 512);
                } else {
                    int row = (ch - 32) * 8 + r8;
                    int gc = col0 + row; if (gc > NPGc - 1) gc = NPGc - 1;
                    llds16(xnl + base + (size_t)gc * HH + k0 + gq * 8,
                           &BslL[0][0] + (ch - 32) * 512);
                }
            }
            __syncthreads();
            #pragma unroll
            for (int ks = 0; ks < 2; ++ks) {
                const int ra = w * 16 + lr;
                short8v ah = *(const short8v*)&AshL[ra][swz(ra, ks * 32 + lk)];
                short8v al = *(const short8v*)&AslL[ra][swz(ra, ks * 32 + lk)];
                #pragma unroll
                for (int n = 0; n < 8; ++n) {
                    const int rbn = n * 16 + lr;
                    short8v bh = *(const short8v*)&BshL[rbn][swz(rbn, ks * 32 + lk)];
                    short8v bl = *(const short8v*)&BslL[rbn][swz(rbn, ks * 32 + lk)];
                    acc[n] = __builtin_amdgcn_mfma_f32_16x16x32_bf16(ah, bh, acc[n], 0, 0, 0);
                    acc[n] = __builtin_amdgcn_mfma_f32_16x16x32_bf16(ah, bl, acc[n], 0, 0, 0);
                    acc[n] = __builtin_amdgcn_mfma_f32_16x16x32_bf16(al, bh, acc[n], 0, 0, 0);
                }
            }
        }
        // fold this col-tile into running top-3 (lane's col = col0 + n*16 + lr)
        #pragma unroll
        for (int r = 0; r < 4; ++r) {
            float a0 = tv0[r], a1 = tv1[r], a2 = tv2[r];
            int   b0 = ti0[r], b1 = ti1[r], b2 = ti2[r];
            #pragma unroll
            for (int n = 0; n < 8; ++n) {
                int col = col0 + n * 16 + lr;
                if (col < NPGc)
                    ins3(acc[n][r], col, a0, b0, a1, b1, a2, b2);
            }
            tv0[r] = a0; tv1[r] = a1; tv2[r] = a2;
            ti0[r] = b0; ti1[r] = b1; ti2[r] = b2;
        }
    }

    #pragma unroll
    for (int r = 0; r < 4; ++r) {
        float a0 = tv0[r], a1 = tv1[r], a2 = tv2[r];
        int   b0 = ti0[r], b1 = ti1[r], b2 = ti2[r];
        #pragma unroll
        for (int off = 1; off <= 8; off <<= 1)
            merge3(a0, a1, a2, b0, b1, b2, off);
        if (lr == 0) {
            int row = row0 + w * 16 + hi4 * 4 + r;
            if (row < NPGc) {
                int rg = g * NPGc + row;
                fsrc[rg * 3 + 0] = g * NPGc + b0;
                fsrc[rg * 3 + 1] = g * NPGc + b1;
                fsrc[rg * 3 + 2] = g * NPGc + b2;
            }
        }
    }
}

// ---------------------------------------------------------------------------
// CSR build
// ---------------------------------------------------------------------------
__global__ void hist_kernel(const int* __restrict__ dst, int* __restrict__ cnt, int nE)
{
    int e = blockIdx.x * 256 + threadIdx.x;
    if (e < nE) atomicAdd(&cnt[dst[e]], 1);
}

__global__ void scan1_kernel(const int* __restrict__ in, int* __restrict__ out,
                             int* __restrict__ bsum, int n)
{
    __shared__ int sh[256];
    int t = threadIdx.x;
    int i = blockIdx.x * 256 + t;
    int v = (i < n) ? in[i] : 0;
    sh[t] = v;
    __syncthreads();
    for (int s = 1; s < 256; s <<= 1) {
        int tv = (t >= s) ? sh[t - s] : 0;
        __syncthreads();
        sh[t] += tv;
        __syncthreads();
    }
    if (i < n) out[i] = sh[t] - v;  // exclusive
    if (t == 255) bsum[blockIdx.x] = sh[255];
}

__global__ void scan2_kernel(int* __restrict__ bsum, int nb)
{
    __shared__ int sh[256];
    int t = threadIdx.x;
    int v = (t < nb) ? bsum[t] : 0;
    sh[t] = v;
    __syncthreads();
    for (int s = 1; s < 256; s <<= 1) {
        int tv = (t >= s) ? sh[t - s] : 0;
        __syncthreads();
        sh[t] += tv;
        __syncthreads();
    }
    if (t < nb) bsum[t] = sh[t] - v;
}

__global__ void scan3_kernel(int* __restrict__ out, const int* __restrict__ bsum, int n)
{
    int i = blockIdx.x * 256 + threadIdx.x;
    if (i < n) out[i] += bsum[blockIdx.x];
}

__global__ void fill_kernel(const int* __restrict__ src, const int* __restrict__ dst,
                            const int* __restrict__ row_ptr, int* __restrict__ cursor,
                            int* __restrict__ sorted_src, int nE)
{
    int e = blockIdx.x * 256 + threadIdx.x;
    if (e < nE) {
        int d = dst[e];
        int pos = row_ptr[d] + atomicAdd(&cursor[d], 1);
        sorted_src[pos] = src[e];
    }
}

__global__ void dinv_kernel(const int* __restrict__ cnt, float* __restrict__ dinv, int n)
{
    int i = blockIdx.x * 256 + threadIdx.x;
    if (i < n) dinv[i] = rsqrtf((float)cnt[i] + 1.0f);
}

// ---------------------------------------------------------------------------
// GCN gather (bf16 messages, XCD-bijective swizzle)
// ---------------------------------------------------------------------------
__global__ __launch_bounds__(256)
void gcn_gather(const ushort* __restrict__ m, const int* __restrict__ row_ptr,
                const int* __restrict__ cnt, const int* __restrict__ srcs,
                const float* __restrict__ dinv, const float* __restrict__ bias,
                float* __restrict__ out)
{
    int bid = blockIdx.x;
    int xcd = bid & 7, idx = bid >> 3;
    int g = xcd + 8 * (idx / NPGc);
    if (g >= GG) return;
    int n = g * NPGc + (idx % NPGc);
    int c = threadIdx.x;
    float dn = dinv[n];
    float acc = bf2f(m[(size_t)n * HH + c]) * dn;
    int s0 = row_ptr[n], e0 = s0 + cnt[n];
    for (int e = s0; e < e0; ++e) {
        int s = srcs[e];
        acc += bf2f(m[(size_t)s * HH + c]) * dinv[s];
    }
    out[(size_t)n * HH + c] = acc * dn + bias[c];
}

__global__ __launch_bounds__(256)
void fgcn_gather(const ushort* __restrict__ m, const int* __restrict__ fsrc,
                 const float* __restrict__ bias, float* __restrict__ out)
{
    int bid = blockIdx.x;
    int xcd = bid & 7, idx = bid >> 3;
    int g = xcd + 8 * (idx / NPGc);
    if (g >= GG) return;
    int n = g * NPGc + (idx % NPGc);
    int c = threadIdx.x;
    int s0 = fsrc[n * 3], s1 = fsrc[n * 3 + 1], s2 = fsrc[n * 3 + 2];
    float acc = bf2f(m[(size_t)n * HH + c]) + bf2f(m[(size_t)s0 * HH + c])
              + bf2f(m[(size_t)s1 * HH + c]) + bf2f(m[(size_t)s2 * HH + c]);
    out[(size_t)n * HH + c] = 0.25f * acc + bias[c];
}

// ---------------------------------------------------------------------------
// GraphNorm: partial stats (no atomics, no memset) + apply reducing partials
// ---------------------------------------------------------------------------
__global__ __launch_bounds__(256)
void norm_stats(const float* __restrict__ x, float* __restrict__ S1p, float* __restrict__ S2p)
{
    int g = blockIdx.x, chunk = blockIdx.y, c = threadIdx.x;
    int r0 = chunk * 63, r1 = min(r0 + 63, NPGc);
    float s1 = 0.f, s2 = 0.f;
    for (int r = r0; r < r1; ++r) {
        float v = x[((size_t)(g * NPGc + r)) * HH + c];
        s1 += v; s2 += v * v;
    }
    size_t o = ((size_t)(g * 8 + chunk)) * HH + c;
    S1p[o] = s1;
    S2p[o] = s2;
}

__global__ __launch_bounds__(256)
void norm_apply(float* __restrict__ x, const float* __restrict__ S1p, const float* __restrict__ S2p,
                const float* __restrict__ w, const float* __restrict__ b,
                const float* __restrict__ ms)
{
    int n = blockIdx.x, c = threadIdx.x;
    int g = n / NPGc;
    size_t o = (size_t)n * HH + c;
    float v = x[o];
    float s1 = 0.f, s2 = 0.f;
    #pragma unroll
    for (int j = 0; j < 8; ++j) {
        size_t po = ((size_t)(g * 8 + j)) * HH + c;
        s1 += S1p[po];
        s2 += S2p[po];
    }
    float mean = s1 / (float)NPGc;
    float mm = mean * ms[c];
    float var = s2 / (float)NPGc - 2.f * mm * mean + mm * mm;
    float outv = w[c] * (v - mm) * rsqrtf(var + 1e-5f) + b[c];
    x[o] = outv > 0.f ? outv : 0.01f * outv;
}

// ---------------------------------------------------------------------------
// Pool: gf[g] = (sum X0 + 2*sum X1) / 500   (all_x[-1]==all_x[1] quirk)
// ---------------------------------------------------------------------------
__global__ __launch_bounds__(256)
void pool_kernel(const float* __restrict__ X0, const float* __restrict__ X1,
                 float* __restrict__ out)
{
    int g = blockIdx.x, c = threadIdx.x;
    float s0 = 0.f, s1 = 0.f;
    for (int r = 0; r < NPGc; ++r) {
        size_t o = ((size_t)(g * NPGc + r)) * HH + c;
        s0 += X0[o];
        s1 += X1[o];
    }
    out[g * HH + c] = (s0 + 2.f * s1) / (float)NPGc;
}

__global__ void sentinel_kernel(float* out, int n)
{
    int i = blockIdx.x * 256 + threadIdx.x;
    if (i < n) out[i] = 12345.0f;
}

// ---------------------------------------------------------------------------
extern "C" void kernel_launch(void* const* d_in, const int* in_sizes, int n_in,
                              void* d_out, int out_size, void* d_ws, size_t ws_size,
                              hipStream_t stream)
{
    const float* x       = (const float*)d_in[0];
    const int* edge_idx  = (const int*)d_in[1];
    const float* emb_W   = (const float*)d_in[3];
    const float* emb_b   = (const float*)d_in[4];
    const float* conv_W  = (const float*)d_in[5];
    const float* conv_b  = (const float*)d_in[6];
    const float* fconv_W = (const float*)d_in[7];
    const float* fconv_b = (const float*)d_in[8];
    const float* norm_w  = (const float*)d_in[9];
    const float* norm_b  = (const float*)d_in[10];
    const float* norm_ms = (const float*)d_in[11];
    const float* fnorm_w = (const float*)d_in[12];
    const float* fnorm_b = (const float*)d_in[13];
    const float* fnorm_ms= (const float*)d_in[14];
    const float* gate_W  = (const float*)d_in[15];
    const float* gate_b  = (const float*)d_in[16];

    const int E = in_sizes[1] / 2;
    const int* esrc = edge_idx;
    const int* edst = edge_idx + E;

    const size_t NHf = (size_t)NN * HH;           // 12.8M elements
    char* p = (char*)d_ws;
    auto alloc = [&](size_t bytes) { char* r = p; p += (bytes + 255) & ~(size_t)255; return r; };
    float* B0 = (float*)alloc(NHf * 4);
    float* B1 = (float*)alloc(NHf * 4);
    float* B2 = (float*)alloc(NHf * 4);
    float* B3 = (float*)alloc(NHf * 4);
    ushort* xnh = (ushort*)B2;          // 25.6MB overlay, dead once layers start
    ushort* xnl = xnh + NHf;            // 25.6MB (rest of B2)
    ushort* msgbf = (ushort*)alloc(NHf * 2);  // bf16 message buffer
    int* sorted_src = (int*)alloc((size_t)E * 4);
    int* row_ptr    = (int*)alloc((size_t)NN * 4);
    int* deg_cnt    = (int*)alloc((size_t)NN * 4);
    int* cursor     = (int*)alloc((size_t)NN * 4);
    float* dinv     = (float*)alloc((size_t)NN * 4);
    int* fsrc       = (int*)alloc((size_t)NN * 3 * 4);
    float* S1p      = (float*)alloc((size_t)GG * 8 * HH * 4);
    float* S2p      = (float*)alloc((size_t)GG * 8 * HH * 4);
    int* bsum       = (int*)alloc(1024);
    ushort* wts     = (ushort*)alloc((size_t)425984 * 2);  // all W^T bf16 (pre-swizzled)
    size_t needed = (size_t)(p - (char*)d_ws);
    if (ws_size < needed) {
        sentinel_kernel<<<(out_size + 255) / 256, 256, 0, stream>>>((float*)d_out, out_size);
        return;
    }
    ushort* embWt   = wts;                    // [256][128]
    ushort* convWt0 = wts + 32768;            // [256][256]
    ushort* convWt1 = wts + 32768 + 65536;
    ushort* fconvWt0 = wts + 163840;
    ushort* fconvWt1 = wts + 163840 + 65536;
    ushort* gateWt  = wts + 294912;           // [256][512]

    const int nScanB = (NN + 255) / 256;  // 196
    const int gatherGrid = 8 * 13 * NPGc; // 52000 (XCD-bijective, skip g>=100)

    hipMemsetAsync(deg_cnt, 0, (size_t)NN * 4, stream);
    hipMemsetAsync(cursor, 0, (size_t)NN * 4, stream);

    // 0. weight transpose+cvt (pre-swizzled for DMA staging)
    wcvt<<<(32768 + 255) / 256, 256, 0, stream>>>(emb_W, embWt, IND, HH);
    wcvt<<<(65536 + 255) / 256, 256, 0, stream>>>(conv_W, convWt0, HH, HH);
    wcvt<<<(65536 + 255) / 256, 256, 0, stream>>>(conv_W + 65536, convWt1, HH, HH);
    wcvt<<<(65536 + 255) / 256, 256, 0, stream>>>(fconv_W, fconvWt0, HH, HH);
    wcvt<<<(65536 + 255) / 256, 256, 0, stream>>>(fconv_W + 65536, fconvWt1, HH, HH);
    wcvt<<<(131072 + 255) / 256, 256, 0, stream>>>(gate_W, gateWt, 2 * HH, HH);

    // 1. embedding: h0 = x @ emb_W + emb_b -> B0
    dim3 ggrid((NN + 127) / 128, 2);
    gemm_mfma<<<ggrid, 256, 0, stream>>>(x, nullptr, embWt, emb_b, B0, nullptr,
                                         NN, IND, IND, 0, nullptr, nullptr, nullptr);

    // 2. CSR of edge_index by dst
    hist_kernel<<<(E + 255) / 256, 256, 0, stream>>>(edst, deg_cnt, E);
    scan1_kernel<<<nScanB, 256, 0, stream>>>(deg_cnt, row_ptr, bsum, NN);
    scan2_kernel<<<1, 256, 0, stream>>>(bsum, nScanB);
    scan3_kernel<<<nScanB, 256, 0, stream>>>(row_ptr, bsum, NN);
    fill_kernel<<<(E + 255) / 256, 256, 0, stream>>>(esrc, edst, row_ptr, cursor, sorted_src, E);
    dinv_kernel<<<(NN + 255) / 256, 256, 0, stream>>>(deg_cnt, dinv, NN);

    // 3. knn graph from h0 (hi/lo split, all-DMA fused sim+topk)
    row_norm_hl<<<NN, 256, 0, stream>>>(B0, xnh, xnl);
    simtopk<<<832, 256, 0, stream>>>(xnh, xnl, fsrc);

    // 4. layers
    float* h  = B0;
    float* mb = B1;
    dim3 ngrid(GG, 8);
    for (int i = 0; i < 2; ++i) {
        const ushort* Wc = (i == 0) ? convWt0 : convWt1;
        const ushort* Wf = (i == 0) ? fconvWt0 : fconvWt1;
        const float* bc  = conv_b  + (size_t)i * HH;
        const float* bf  = fconv_b + (size_t)i * HH;
        // h-road conv -> bf16 messages
        gemm_mfma<<<ggrid, 256, 0, stream>>>(h, nullptr, Wc, nullptr, nullptr, msgbf,
                                             NN, HH, HH, 2, nullptr, nullptr, nullptr);
        gcn_gather<<<gatherGrid, 256, 0, stream>>>(msgbf, row_ptr, deg_cnt, sorted_src,
                                                   dinv, bc, B2);
        norm_stats<<<ngrid, 256, 0, stream>>>(B2, S1p, S2p);
        norm_apply<<<NN, 256, 0, stream>>>(B2, S1p, S2p, norm_w + i * HH, norm_b + i * HH,
                                           norm_ms + i * HH);
        // f-road conv (knn graph) -> bf16 messages
        gemm_mfma<<<ggrid, 256, 0, stream>>>(B2, nullptr, Wf, nullptr, nullptr, msgbf,
                                             NN, HH, HH, 2, nullptr, nullptr, nullptr);
        fgcn_gather<<<gatherGrid, 256, 0, stream>>>(msgbf, fsrc, bf, B3);
        norm_stats<<<ngrid, 256, 0, stream>>>(B3, S1p, S2p);
        norm_apply<<<NN, 256, 0, stream>>>(B3, S1p, S2p, fnorm_w + i * HH, fnorm_b + i * HH,
                                           fnorm_ms + i * HH);
        // gate + combine
        gemm_mfma<<<ggrid, 256, 0, stream>>>(B2, B3, gateWt, gate_b, mb, nullptr,
                                             NN, 2 * HH, HH, 1, B2, B3, h);
        float* t = h; h = mb; mb = t;
    }
    // h = all_x[1], mb = all_x[0]
    pool_kernel<<<GG, 256, 0, stream>>>(mb, h, (float*)d_out);
}

// Round 12
// 1321.166 us; speedup vs baseline: 1.1226x; 1.1226x over previous
//
#include <hip/hip_runtime.h>
#include <math.h>

#define NN 50000      // nodes
#define GG 100        // graphs
#define NPGc 500      // nodes per graph
#define HH 256        // hidden
#define IND 128       // input dim

typedef __attribute__((ext_vector_type(8))) short short8v;  // 8 bf16
typedef __attribute__((ext_vector_type(4))) float f32x4;

__device__ __forceinline__ ushort f2bf(float f) {
    union { float f; unsigned u; } v; v.f = f;
    unsigned r = (v.u + 0x7fffu + ((v.u >> 16) & 1u)) >> 16;  // RNE
    return (ushort)r;
}
__device__ __forceinline__ float bf2f(ushort h) {
    union { unsigned u; float f; } v; v.u = ((unsigned)h) << 16;
    return v.f;
}

// LDS ushort-index swizzle: XOR 16B-granule bits with row&7 (T2)
__device__ __forceinline__ int swz(int row, int kidx) { return kidx ^ ((row & 7) << 3); }

// ---------------------------------------------------------------------------
// Weight transpose+convert: src [K][N] f32 -> dst [N][K] bf16 (linear)
// ---------------------------------------------------------------------------
__global__ void wcvt(const float* __restrict__ src, ushort* __restrict__ dst, int K, int N)
{
    int i = blockIdx.x * 256 + threadIdx.x;
    if (i < K * N) {
        int n = i / K, k = i % K;
        dst[i] = f2bf(src[(size_t)k * N + n]);
    }
}

// ---------------------------------------------------------------------------
// bf16 MFMA GEMM: C[M x 256] = A[M x K] @ Wt[N=256][K](bf16)
// A is f32 (abf=0, cvt on stage) or bf16 (abf=1, direct 16B copies).
// tile 128x128, BK=64, 4 waves each 64x64. LDS XOR-swizzled.
// mode 0: C=f32(+bias). mode 1: gate epilogue -> Cbf bf16. mode 2: Cbf bf16(+bias).
// ---------------------------------------------------------------------------
__global__ __launch_bounds__(256)
void gemm_mfma(const void* __restrict__ Av, const void* __restrict__ A2v, int abf,
               const ushort* __restrict__ Wt, const float* __restrict__ bias,
               float* __restrict__ C, ushort* __restrict__ Cbf,
               int M, int K, int lda, int mode,
               const ushort* __restrict__ hn, const ushort* __restrict__ fn,
               const void* __restrict__ prevv, int prevbf)
{
    __shared__ ushort As[128][64];
    __shared__ ushort Bs[128][64];
    const int tid = threadIdx.x;
    const int lane = tid & 63;
    const int w = tid >> 6;
    const int wr = (w >> 1) * 64, wc = (w & 1) * 64;
    const int row0 = blockIdx.x * 128, col0 = blockIdx.y * 128;
    const int lr = lane & 15, lk = (lane >> 4) * 8;
    f32x4 acc[4][4] = {};

    for (int k0 = 0; k0 < K; k0 += 64) {
        __syncthreads();
        #pragma unroll
        for (int it = 0; it < 4; ++it) {           // stage A: 128x64
            int c = it * 256 + tid;
            int row = c >> 3, col = (c & 7) * 8;
            int gr = row0 + row; if (gr > M - 1) gr = M - 1;
            int kk = k0 + col;
            if (abf) {
                const ushort* Ap = (const ushort*)Av;
                if (A2v != nullptr && kk >= 256) { Ap = (const ushort*)A2v; kk -= 256; }
                *(int4*)&As[row][swz(row, col)] =
                    *(const int4*)&Ap[(size_t)gr * lda + kk];
            } else {
                const float* Ap = (const float*)Av;
                if (A2v != nullptr && kk >= 256) { Ap = (const float*)A2v; kk -= 256; }
                const float* s = &Ap[(size_t)gr * lda + kk];
                float4 v0 = *(const float4*)s;
                float4 v1 = *(const float4*)(s + 4);
                union { ushort u[8]; int4 q; } pk;
                pk.u[0] = f2bf(v0.x); pk.u[1] = f2bf(v0.y); pk.u[2] = f2bf(v0.z); pk.u[3] = f2bf(v0.w);
                pk.u[4] = f2bf(v1.x); pk.u[5] = f2bf(v1.y); pk.u[6] = f2bf(v1.z); pk.u[7] = f2bf(v1.w);
                *(int4*)&As[row][swz(row, col)] = pk.q;
            }
        }
        #pragma unroll
        for (int it = 0; it < 4; ++it) {           // stage B: Wt rows col0..+127
            int c = it * 256 + tid;
            int n = c >> 3, k = (c & 7) * 8;
            *(int4*)&Bs[n][swz(n, k)] = *(const int4*)&Wt[(size_t)(col0 + n) * K + k0 + k];
        }
        __syncthreads();
        #pragma unroll
        for (int ks = 0; ks < 2; ++ks) {
            short8v av[4], bv[4];
            #pragma unroll
            for (int m = 0; m < 4; ++m) {
                int rr = wr + m * 16 + lr;
                av[m] = *(const short8v*)&As[rr][swz(rr, ks * 32 + lk)];
            }
            #pragma unroll
            for (int n = 0; n < 4; ++n) {
                int rr = wc + n * 16 + lr;
                bv[n] = *(const short8v*)&Bs[rr][swz(rr, ks * 32 + lk)];
            }
            #pragma unroll
            for (int m = 0; m < 4; ++m)
                #pragma unroll
                for (int n = 0; n < 4; ++n)
                    acc[m][n] = __builtin_amdgcn_mfma_f32_16x16x32_bf16(av[m], bv[n], acc[m][n], 0, 0, 0);
        }
    }
    const int fr = (lane >> 4) * 4;
    if (mode == 0) {
        #pragma unroll
        for (int n = 0; n < 4; ++n) {
            int col = col0 + wc + n * 16 + lr;
            float bb = bias ? bias[col] : 0.f;
            #pragma unroll
            for (int m = 0; m < 4; ++m) {
                int rbase = row0 + wr + m * 16 + fr;
                #pragma unroll
                for (int r = 0; r < 4; ++r) {
                    int row = rbase + r;
                    if (row < M) C[(size_t)row * HH + col] = acc[m][n][r] + bb;
                }
            }
        }
    } else if (mode == 2) {
        #pragma unroll
        for (int n = 0; n < 4; ++n) {
            int col = col0 + wc + n * 16 + lr;
            float bb = bias ? bias[col] : 0.f;
            #pragma unroll
            for (int m = 0; m < 4; ++m) {
                int rbase = row0 + wr + m * 16 + fr;
                #pragma unroll
                for (int r = 0; r < 4; ++r) {
                    int row = rbase + r;
                    if (row < M) Cbf[(size_t)row * HH + col] = f2bf(acc[m][n][r] + bb);
                }
            }
        }
    } else {
        #pragma unroll
        for (int n = 0; n < 4; ++n) {
            int col = col0 + wc + n * 16 + lr;
            float gb = bias[col];
            #pragma unroll
            for (int m = 0; m < 4; ++m) {
                int rbase = row0 + wr + m * 16 + fr;
                #pragma unroll
                for (int r = 0; r < 4; ++r) {
                    int row = rbase + r;
                    if (row < M) {
                        size_t o = (size_t)row * HH + col;
                        float z = acc[m][n][r] + gb;
                        float s = 1.f / (1.f + expf(-z));
                        float hv = bf2f(hn[o]);
                        float fv = bf2f(fn[o]);
                        float pv = prevbf ? bf2f(((const ushort*)prevv)[o])
                                          : ((const float*)prevv)[o];
                        Cbf[o] = f2bf(s * hv + (1.f - s) * fv + pv);
                    }
                }
            }
        }
    }
}

// ---------------------------------------------------------------------------
// Row L2-normalize (f32 in), emit bf16 hi/lo split (linear layout)
// ---------------------------------------------------------------------------
__global__ __launch_bounds__(256)
void row_norm_hl(const float* __restrict__ h, ushort* __restrict__ xh, ushort* __restrict__ xl)
{
    int n = blockIdx.x, c = threadIdx.x;
    float v = h[(size_t)n * HH + c];
    __shared__ float red[256];
    red[c] = v * v;
    __syncthreads();
    for (int s = 128; s > 0; s >>= 1) {
        if (c < s) red[c] += red[c + s];
        __syncthreads();
    }
    float norm = sqrtf(red[0]);
    float xn = v / (norm + 1e-12f);
    ushort hi = f2bf(xn);
    xh[(size_t)n * HH + c] = hi;
    xl[(size_t)n * HH + c] = f2bf(xn - bf2f(hi));
}

// ---------------------------------------------------------------------------
// top-3 helpers (exact top_k tie-breaking: value desc, index asc)
// ---------------------------------------------------------------------------
__device__ __forceinline__ bool tk_better(float va, int ia, float vb, int ib)
{
    return (va > vb) || (va == vb && ia < ib);
}

__device__ __forceinline__ void ins3(float v, int i,
                                     float& a0, int& b0, float& a1, int& b1,
                                     float& a2, int& b2)
{
    if (tk_better(v, i, a0, b0))      { a2 = a1; b2 = b1; a1 = a0; b1 = b0; a0 = v; b0 = i; }
    else if (tk_better(v, i, a1, b1)) { a2 = a1; b2 = b1; a1 = v;  b1 = i; }
    else if (tk_better(v, i, a2, b2)) { a2 = v;  b2 = i; }
}

__device__ __forceinline__ void merge3(float& v0, float& v1, float& v2,
                                       int& i0, int& i1, int& i2, int off)
{
    float w0 = __shfl_xor(v0, off), w1 = __shfl_xor(v1, off), w2 = __shfl_xor(v2, off);
    int   j0 = __shfl_xor(i0, off), j1 = __shfl_xor(i1, off), j2 = __shfl_xor(i2, off);
    float avv[3] = { v0, v1, v2 }, bvv[3] = { w0, w1, w2 };
    int   aii[3] = { i0, i1, i2 }, bii[3] = { j0, j1, j2 };
    float rv[3]; int ri[3];
    int p = 0, q = 0;
    #pragma unroll
    for (int t = 0; t < 3; ++t) {
        bool takeA = tk_better(avv[p], aii[p], bvv[q], bii[q]);
        rv[t] = takeA ? avv[p] : bvv[q];
        ri[t] = takeA ? aii[p] : bii[q];
        if (takeA) ++p; else ++q;
    }
    v0 = rv[0]; v1 = rv[1]; v2 = rv[2];
    i0 = ri[0]; i1 = ri[1]; i2 = ri[2];
}

// ---------------------------------------------------------------------------
// simtopk (round-8 variant, best measured 306us): reg-A + dbuf-B fused
// sim + top-3. Block = 64 rows of one graph; wave = 16 rows x 128 cols.
// B double-buffered in LDS 32-k chunks, issue-early/write-late (T14).
// XCD-swizzled grid. launch_bounds(256,1).
// ---------------------------------------------------------------------------
__global__ __launch_bounds__(256, 1)
void simtopk(const ushort* __restrict__ xnh, const ushort* __restrict__ xnl,
             int* __restrict__ fsrc)
{
    __shared__ ushort Bs[2][2][128][36];   // [buf][hi/lo][col][k(32)+pad4] = 36 KB
    const int bid = blockIdx.x;
    const int xcd = bid & 7;
    const int rb  = (bid >> 3) & 7;
    const int g   = (bid >> 6) * 8 + xcd;
    if (g >= GG) return;
    const int row0 = rb * 64;
    const int tid  = threadIdx.x;
    const int lane = tid & 63;
    const int w    = tid >> 6;
    const int lr   = lane & 15;
    const int hi4  = lane >> 4;
    const size_t base = (size_t)g * NPGc * HH;

    // ---- A fragments in registers: full K, wave's 16 rows ----
    int arow = row0 + w * 16 + lr; if (arow > NPGc - 1) arow = NPGc - 1;
    const ushort* aph = xnh + base + (size_t)arow * HH + hi4 * 8;
    const ushort* apl = xnl + base + (size_t)arow * HH + hi4 * 8;
    short8v ah[8], al[8];
    #pragma unroll
    for (int kc = 0; kc < 8; ++kc) {
        ah[kc] = *(const short8v*)(aph + kc * 32);
        al[kc] = *(const short8v*)(apl + kc * 32);
    }

    const int scol = tid >> 1;             // 0..127
    const int sq   = (tid & 1) * 2;        // granule 0 or 2

    float tv0[4], tv1[4], tv2[4];
    int   ti0[4], ti1[4], ti2[4];
    #pragma unroll
    for (int r = 0; r < 4; ++r) {
        tv0[r] = tv1[r] = tv2[r] = -2.f;
        ti0[r] = ti1[r] = ti2[r] = 0x7fffffff;
    }

    for (int ct = 0; ct < 4; ++ct) {
        const int col0 = ct * 128;
        int gcol = col0 + scol; if (gcol > NPGc - 1) gcol = NPGc - 1;
        const ushort* sph = xnh + base + (size_t)gcol * HH + sq * 8;
        const ushort* spl = xnl + base + (size_t)gcol * HH + sq * 8;

        {
            int4 h0 = *(const int4*)(sph);
            int4 h1 = *(const int4*)(sph + 8);
            int4 l0 = *(const int4*)(spl);
            int4 l1 = *(const int4*)(spl + 8);
            *(int4*)&Bs[0][0][scol][sq * 8]     = h0;
            *(int4*)&Bs[0][0][scol][sq * 8 + 8] = h1;
            *(int4*)&Bs[0][1][scol][sq * 8]     = l0;
            *(int4*)&Bs[0][1][scol][sq * 8 + 8] = l1;
        }
        __syncthreads();

        f32x4 acc[8] = {};
        #pragma unroll
        for (int kc = 0; kc < 8; ++kc) {
            const int cur = kc & 1, nxt = cur ^ 1;
            int4 h0, h1, l0, l1;
            if (kc < 7) {
                const ushort* nh = sph + (kc + 1) * 32;
                const ushort* nl = spl + (kc + 1) * 32;
                h0 = *(const int4*)(nh);
                h1 = *(const int4*)(nh + 8);
                l0 = *(const int4*)(nl);
                l1 = *(const int4*)(nl + 8);
            }
            short8v bh[8], bl[8];
            #pragma unroll
            for (int n = 0; n < 8; ++n) {
                int rr = n * 16 + lr;
                bh[n] = *(const short8v*)&Bs[cur][0][rr][hi4 * 8];
                bl[n] = *(const short8v*)&Bs[cur][1][rr][hi4 * 8];
            }
            #pragma unroll
            for (int n = 0; n < 8; ++n) {
                acc[n] = __builtin_amdgcn_mfma_f32_16x16x32_bf16(ah[kc], bh[n], acc[n], 0, 0, 0);
                acc[n] = __builtin_amdgcn_mfma_f32_16x16x32_bf16(ah[kc], bl[n], acc[n], 0, 0, 0);
                acc[n] = __builtin_amdgcn_mfma_f32_16x16x32_bf16(al[kc], bh[n], acc[n], 0, 0, 0);
            }
            if (kc < 7) {
                *(int4*)&Bs[nxt][0][scol][sq * 8]     = h0;
                *(int4*)&Bs[nxt][0][scol][sq * 8 + 8] = h1;
                *(int4*)&Bs[nxt][1][scol][sq * 8]     = l0;
                *(int4*)&Bs[nxt][1][scol][sq * 8 + 8] = l1;
            }
            __syncthreads();
        }

        #pragma unroll
        for (int r = 0; r < 4; ++r) {
            float a0 = tv0[r], a1 = tv1[r], a2 = tv2[r];
            int   b0 = ti0[r], b1 = ti1[r], b2 = ti2[r];
            #pragma unroll
            for (int n = 0; n < 8; ++n) {
                int col = col0 + n * 16 + lr;
                if (col < NPGc)
                    ins3(acc[n][r], col, a0, b0, a1, b1, a2, b2);
            }
            tv0[r] = a0; tv1[r] = a1; tv2[r] = a2;
            ti0[r] = b0; ti1[r] = b1; ti2[r] = b2;
        }
    }

    #pragma unroll
    for (int r = 0; r < 4; ++r) {
        float a0 = tv0[r], a1 = tv1[r], a2 = tv2[r];
        int   b0 = ti0[r], b1 = ti1[r], b2 = ti2[r];
        #pragma unroll
        for (int off = 1; off <= 8; off <<= 1)
            merge3(a0, a1, a2, b0, b1, b2, off);
        if (lr == 0) {
            int row = row0 + w * 16 + hi4 * 4 + r;
            if (row < NPGc) {
                int rg = g * NPGc + row;
                fsrc[rg * 3 + 0] = g * NPGc + b0;
                fsrc[rg * 3 + 1] = g * NPGc + b1;
                fsrc[rg * 3 + 2] = g * NPGc + b2;
            }
        }
    }
}

// ---------------------------------------------------------------------------
// CSR build
// ---------------------------------------------------------------------------
__global__ void hist_kernel(const int* __restrict__ dst, int* __restrict__ cnt, int nE)
{
    int e = blockIdx.x * 256 + threadIdx.x;
    if (e < nE) atomicAdd(&cnt[dst[e]], 1);
}

__global__ void scan1_kernel(const int* __restrict__ in, int* __restrict__ out,
                             int* __restrict__ bsum, int n)
{
    __shared__ int sh[256];
    int t = threadIdx.x;
    int i = blockIdx.x * 256 + t;
    int v = (i < n) ? in[i] : 0;
    sh[t] = v;
    __syncthreads();
    for (int s = 1; s < 256; s <<= 1) {
        int tv = (t >= s) ? sh[t - s] : 0;
        __syncthreads();
        sh[t] += tv;
        __syncthreads();
    }
    if (i < n) out[i] = sh[t] - v;  // exclusive
    if (t == 255) bsum[blockIdx.x] = sh[255];
}

__global__ void scan2_kernel(int* __restrict__ bsum, int nb)
{
    __shared__ int sh[256];
    int t = threadIdx.x;
    int v = (t < nb) ? bsum[t] : 0;
    sh[t] = v;
    __syncthreads();
    for (int s = 1; s < 256; s <<= 1) {
        int tv = (t >= s) ? sh[t - s] : 0;
        __syncthreads();
        sh[t] += tv;
        __syncthreads();
    }
    if (t < nb) bsum[t] = sh[t] - v;
}

__global__ void scan3_kernel(int* __restrict__ out, const int* __restrict__ bsum, int n)
{
    int i = blockIdx.x * 256 + threadIdx.x;
    if (i < n) out[i] += bsum[blockIdx.x];
}

__global__ void fill_kernel(const int* __restrict__ src, const int* __restrict__ dst,
                            const int* __restrict__ row_ptr, int* __restrict__ cursor,
                            int* __restrict__ sorted_src, int nE)
{
    int e = blockIdx.x * 256 + threadIdx.x;
    if (e < nE) {
        int d = dst[e];
        int pos = row_ptr[d] + atomicAdd(&cursor[d], 1);
        sorted_src[pos] = src[e];
    }
}

__global__ void dinv_kernel(const int* __restrict__ cnt, float* __restrict__ dinv, int n)
{
    int i = blockIdx.x * 256 + threadIdx.x;
    if (i < n) dinv[i] = rsqrtf((float)cnt[i] + 1.0f);
}

// ---------------------------------------------------------------------------
// GCN gather (bf16 messages in, bf16 out, XCD-bijective swizzle)
// ---------------------------------------------------------------------------
__global__ __launch_bounds__(256)
void gcn_gather(const ushort* __restrict__ m, const int* __restrict__ row_ptr,
                const int* __restrict__ cnt, const int* __restrict__ srcs,
                const float* __restrict__ dinv, const float* __restrict__ bias,
                ushort* __restrict__ out)
{
    int bid = blockIdx.x;
    int xcd = bid & 7, idx = bid >> 3;
    int g = xcd + 8 * (idx / NPGc);
    if (g >= GG) return;
    int n = g * NPGc + (idx % NPGc);
    int c = threadIdx.x;
    float dn = dinv[n];
    float acc = bf2f(m[(size_t)n * HH + c]) * dn;
    int s0 = row_ptr[n], e0 = s0 + cnt[n];
    for (int e = s0; e < e0; ++e) {
        int s = srcs[e];
        acc += bf2f(m[(size_t)s * HH + c]) * dinv[s];
    }
    out[(size_t)n * HH + c] = f2bf(acc * dn + bias[c]);
}

__global__ __launch_bounds__(256)
void fgcn_gather(const ushort* __restrict__ m, const int* __restrict__ fsrc,
                 const float* __restrict__ bias, ushort* __restrict__ out)
{
    int bid = blockIdx.x;
    int xcd = bid & 7, idx = bid >> 3;
    int g = xcd + 8 * (idx / NPGc);
    if (g >= GG) return;
    int n = g * NPGc + (idx % NPGc);
    int c = threadIdx.x;
    int s0 = fsrc[n * 3], s1 = fsrc[n * 3 + 1], s2 = fsrc[n * 3 + 2];
    float acc = bf2f(m[(size_t)n * HH + c]) + bf2f(m[(size_t)s0 * HH + c])
              + bf2f(m[(size_t)s1 * HH + c]) + bf2f(m[(size_t)s2 * HH + c]);
    out[(size_t)n * HH + c] = f2bf(0.25f * acc + bias[c]);
}

// ---------------------------------------------------------------------------
// GraphNorm: partial stats (no atomics/memsets) + apply reducing partials.
// bf16 activations, in-place apply.
// ---------------------------------------------------------------------------
__global__ __launch_bounds__(256)
void norm_stats(const ushort* __restrict__ x, float* __restrict__ S1p, float* __restrict__ S2p)
{
    int g = blockIdx.x, chunk = blockIdx.y, c = threadIdx.x;
    int r0 = chunk * 63, r1 = min(r0 + 63, NPGc);
    float s1 = 0.f, s2 = 0.f;
    for (int r = r0; r < r1; ++r) {
        float v = bf2f(x[((size_t)(g * NPGc + r)) * HH + c]);
        s1 += v; s2 += v * v;
    }
    size_t o = ((size_t)(g * 8 + chunk)) * HH + c;
    S1p[o] = s1;
    S2p[o] = s2;
}

__global__ __launch_bounds__(256)
void norm_apply(ushort* __restrict__ x, const float* __restrict__ S1p, const float* __restrict__ S2p,
                const float* __restrict__ w, const float* __restrict__ b,
                const float* __restrict__ ms)
{
    int n = blockIdx.x, c = threadIdx.x;
    int g = n / NPGc;
    size_t o = (size_t)n * HH + c;
    float v = bf2f(x[o]);
    float s1 = 0.f, s2 = 0.f;
    #pragma unroll
    for (int j = 0; j < 8; ++j) {
        size_t po = ((size_t)(g * 8 + j)) * HH + c;
        s1 += S1p[po];
        s2 += S2p[po];
    }
    float mean = s1 / (float)NPGc;
    float mm = mean * ms[c];
    float var = s2 / (float)NPGc - 2.f * mm * mean + mm * mm;
    float outv = w[c] * (v - mm) * rsqrtf(var + 1e-5f) + b[c];
    x[o] = f2bf(outv > 0.f ? outv : 0.01f * outv);
}

// ---------------------------------------------------------------------------
// Pool: gf[g] = (sum H0 + 2*sum H1) / 500   (all_x[-1]==all_x[1] quirk)
// ---------------------------------------------------------------------------
__global__ __launch_bounds__(256)
void pool_kernel(const ushort* __restrict__ X0, const ushort* __restrict__ X1,
                 float* __restrict__ out)
{
    int g = blockIdx.x, c = threadIdx.x;
    float s0 = 0.f, s1 = 0.f;
    for (int r = 0; r < NPGc; ++r) {
        size_t o = ((size_t)(g * NPGc + r)) * HH + c;
        s0 += bf2f(X0[o]);
        s1 += bf2f(X1[o]);
    }
    out[g * HH + c] = (s0 + 2.f * s1) / (float)NPGc;
}

__global__ void sentinel_kernel(float* out, int n)
{
    int i = blockIdx.x * 256 + threadIdx.x;
    if (i < n) out[i] = 12345.0f;
}

// ---------------------------------------------------------------------------
extern "C" void kernel_launch(void* const* d_in, const int* in_sizes, int n_in,
                              void* d_out, int out_size, void* d_ws, size_t ws_size,
                              hipStream_t stream)
{
    const float* x       = (const float*)d_in[0];
    const int* edge_idx  = (const int*)d_in[1];
    const float* emb_W   = (const float*)d_in[3];
    const float* emb_b   = (const float*)d_in[4];
    const float* conv_W  = (const float*)d_in[5];
    const float* conv_b  = (const float*)d_in[6];
    const float* fconv_W = (const float*)d_in[7];
    const float* fconv_b = (const float*)d_in[8];
    const float* norm_w  = (const float*)d_in[9];
    const float* norm_b  = (const float*)d_in[10];
    const float* norm_ms = (const float*)d_in[11];
    const float* fnorm_w = (const float*)d_in[12];
    const float* fnorm_b = (const float*)d_in[13];
    const float* fnorm_ms= (const float*)d_in[14];
    const float* gate_W  = (const float*)d_in[15];
    const float* gate_b  = (const float*)d_in[16];

    const int E = in_sizes[1] / 2;
    const int* esrc = edge_idx;
    const int* edst = edge_idx + E;

    const size_t NHf = (size_t)NN * HH;           // 12.8M elements
    char* p = (char*)d_ws;
    auto alloc = [&](size_t bytes) { char* r = p; p += (bytes + 255) & ~(size_t)255; return r; };
    float*  B0 = (float*)alloc(NHf * 4);          // emb out (f32, feeds knn)
    ushort* Mr = (ushort*)alloc(NHf * 2);         // messages
    ushort* Ar = (ushort*)alloc(NHf * 2);         // h-road act (gather->normed)
    ushort* Br = (ushort*)alloc(NHf * 2);         // f-road act
    ushort* H0 = (ushort*)alloc(NHf * 2);         // layer0 out
    ushort* H1 = (ushort*)alloc(NHf * 2);         // layer1 out
    ushort* xnh = Mr;                             // knn operands overlay Mr/Ar
    ushort* xnl = Ar;                             // (dead before layers start)
    int* sorted_src = (int*)alloc((size_t)E * 4);
    int* row_ptr    = (int*)alloc((size_t)NN * 4);
    int* deg_cnt    = (int*)alloc((size_t)NN * 4);
    int* cursor     = (int*)alloc((size_t)NN * 4);
    float* dinv     = (float*)alloc((size_t)NN * 4);
    int* fsrc       = (int*)alloc((size_t)NN * 3 * 4);
    float* S1p      = (float*)alloc((size_t)GG * 8 * HH * 4);
    float* S2p      = (float*)alloc((size_t)GG * 8 * HH * 4);
    int* bsum       = (int*)alloc(1024);
    ushort* wts     = (ushort*)alloc((size_t)425984 * 2);  // all W^T bf16
    size_t needed = (size_t)(p - (char*)d_ws);
    if (ws_size < needed) {
        sentinel_kernel<<<(out_size + 255) / 256, 256, 0, stream>>>((float*)d_out, out_size);
        return;
    }
    ushort* embWt   = wts;                    // [256][128]
    ushort* convWt0 = wts + 32768;            // [256][256]
    ushort* convWt1 = wts + 32768 + 65536;
    ushort* fconvWt0 = wts + 163840;
    ushort* fconvWt1 = wts + 163840 + 65536;
    ushort* gateWt  = wts + 294912;           // [256][512]

    const int nScanB = (NN + 255) / 256;  // 196
    const int gatherGrid = 8 * 13 * NPGc; // 52000 (XCD-bijective, skip g>=100)

    hipMemsetAsync(deg_cnt, 0, (size_t)NN * 4, stream);
    hipMemsetAsync(cursor, 0, (size_t)NN * 4, stream);

    // 0. weight transpose+cvt
    wcvt<<<(32768 + 255) / 256, 256, 0, stream>>>(emb_W, embWt, IND, HH);
    wcvt<<<(65536 + 255) / 256, 256, 0, stream>>>(conv_W, convWt0, HH, HH);
    wcvt<<<(65536 + 255) / 256, 256, 0, stream>>>(conv_W + 65536, convWt1, HH, HH);
    wcvt<<<(65536 + 255) / 256, 256, 0, stream>>>(fconv_W, fconvWt0, HH, HH);
    wcvt<<<(65536 + 255) / 256, 256, 0, stream>>>(fconv_W + 65536, fconvWt1, HH, HH);
    wcvt<<<(131072 + 255) / 256, 256, 0, stream>>>(gate_W, gateWt, 2 * HH, HH);

    // 1. embedding: h0 = x @ emb_W + emb_b -> B0 (f32)
    dim3 ggrid((NN + 127) / 128, 2);
    gemm_mfma<<<ggrid, 256, 0, stream>>>(x, nullptr, 0, embWt, emb_b, B0, nullptr,
                                         NN, IND, IND, 0, nullptr, nullptr, nullptr, 0);

    // 2. CSR of edge_index by dst
    hist_kernel<<<(E + 255) / 256, 256, 0, stream>>>(edst, deg_cnt, E);
    scan1_kernel<<<nScanB, 256, 0, stream>>>(deg_cnt, row_ptr, bsum, NN);
    scan2_kernel<<<1, 256, 0, stream>>>(bsum, nScanB);
    scan3_kernel<<<nScanB, 256, 0, stream>>>(row_ptr, bsum, NN);
    fill_kernel<<<(E + 255) / 256, 256, 0, stream>>>(esrc, edst, row_ptr, cursor, sorted_src, E);
    dinv_kernel<<<(NN + 255) / 256, 256, 0, stream>>>(deg_cnt, dinv, NN);

    // 3. knn graph from h0 (hi/lo split, fused sim+topk)
    row_norm_hl<<<NN, 256, 0, stream>>>(B0, xnh, xnl);
    simtopk<<<832, 256, 0, stream>>>(xnh, xnl, fsrc);

    // 4. layers (bf16 activations throughout)
    dim3 ngrid(GG, 8);
    const void* hptr = (const void*)B0;   // prev/conv-input; f32 for layer 0
    int habf = 0;
    ushort* Hout[2] = { H0, H1 };
    for (int i = 0; i < 2; ++i) {
        const ushort* Wc = (i == 0) ? convWt0 : convWt1;
        const ushort* Wf = (i == 0) ? fconvWt0 : fconvWt1;
        const float* bc  = conv_b  + (size_t)i * HH;
        const float* bf  = fconv_b + (size_t)i * HH;
        // h-road conv -> bf16 messages
        gemm_mfma<<<ggrid, 256, 0, stream>>>(hptr, nullptr, habf, Wc, nullptr, nullptr, Mr,
                                             NN, HH, HH, 2, nullptr, nullptr, nullptr, 0);
        gcn_gather<<<gatherGrid, 256, 0, stream>>>(Mr, row_ptr, deg_cnt, sorted_src,
                                                   dinv, bc, Ar);
        norm_stats<<<ngrid, 256, 0, stream>>>(Ar, S1p, S2p);
        norm_apply<<<NN, 256, 0, stream>>>(Ar, S1p, S2p, norm_w + i * HH, norm_b + i * HH,
                                           norm_ms + i * HH);
        // f-road conv (knn graph) -> bf16 messages
        gemm_mfma<<<ggrid, 256, 0, stream>>>(Ar, nullptr, 1, Wf, nullptr, nullptr, Mr,
                                             NN, HH, HH, 2, nullptr, nullptr, nullptr, 0);
        fgcn_gather<<<gatherGrid, 256, 0, stream>>>(Mr, fsrc, bf, Br);
        norm_stats<<<ngrid, 256, 0, stream>>>(Br, S1p, S2p);
        norm_apply<<<NN, 256, 0, stream>>>(Br, S1p, S2p, fnorm_w + i * HH, fnorm_b + i * HH,
                                           fnorm_ms + i * HH);
        // gate + combine -> bf16 H_i
        gemm_mfma<<<ggrid, 256, 0, stream>>>(Ar, Br, 1, gateWt, gate_b, nullptr, Hout[i],
                                             NN, 2 * HH, HH, 1, Ar, Br, hptr, habf);
        hptr = (const void*)Hout[i];
        habf = 1;
    }
    // all_x[0]=H0, all_x[1]=H1: gf = (sum H0 + 2*sum H1)/500
    pool_kernel<<<GG, 256, 0, stream>>>(H0, H1, (float*)d_out);
}

// Round 13
// 1264.064 us; speedup vs baseline: 1.1734x; 1.0452x over previous
//
#include <hip/hip_runtime.h>
#include <math.h>

#define NN 50000      // nodes
#define GG 100        // graphs
#define NPGc 500      // nodes per graph
#define HH 256        // hidden
#define IND 128       // input dim

typedef __attribute__((ext_vector_type(8))) short short8v;  // 8 bf16
typedef __attribute__((ext_vector_type(4))) float f32x4;

__device__ __forceinline__ ushort f2bf(float f) {
    union { float f; unsigned u; } v; v.f = f;
    unsigned r = (v.u + 0x7fffu + ((v.u >> 16) & 1u)) >> 16;  // RNE
    return (ushort)r;
}
__device__ __forceinline__ float bf2f(ushort h) {
    union { unsigned u; float f; } v; v.u = ((unsigned)h) << 16;
    return v.f;
}

// LDS ushort-index swizzle: XOR 16B-granule bits with row&7 (T2)
__device__ __forceinline__ int swz(int row, int kidx) { return kidx ^ ((row & 7) << 3); }

// ---------------------------------------------------------------------------
// All weight transposes+converts in ONE launch. dst layout (ushort elems):
// [0,32768)      embWt   [256][128]
// [32768,98304)  convWt0 [256][256]
// [98304,163840) convWt1
// [163840,229376) fconvWt0
// [229376,294912) fconvWt1
// [294912,425984) gateWt [256][512]
// ---------------------------------------------------------------------------
__global__ void wcvt_all(const float* __restrict__ emb_W, const float* __restrict__ conv_W,
                         const float* __restrict__ fconv_W, const float* __restrict__ gate_W,
                         ushort* __restrict__ dst)
{
    int i = blockIdx.x * 256 + threadIdx.x;
    if (i >= 425984) return;
    float v;
    if (i < 32768)       { int n = i >> 7, k = i & 127;              v = emb_W[(size_t)k * 256 + n]; }
    else if (i < 98304)  { int j = i - 32768;  int n = j >> 8, k = j & 255; v = conv_W[(size_t)k * 256 + n]; }
    else if (i < 163840) { int j = i - 98304;  int n = j >> 8, k = j & 255; v = conv_W[65536 + (size_t)k * 256 + n]; }
    else if (i < 229376) { int j = i - 163840; int n = j >> 8, k = j & 255; v = fconv_W[(size_t)k * 256 + n]; }
    else if (i < 294912) { int j = i - 229376; int n = j >> 8, k = j & 255; v = fconv_W[65536 + (size_t)k * 256 + n]; }
    else                 { int j = i - 294912; int n = j >> 9, k = j & 511; v = gate_W[(size_t)k * 256 + n]; }
    dst[i] = f2bf(v);
}

// ---------------------------------------------------------------------------
// bf16 MFMA GEMM: C[M x 256] = A[M x K] @ Wt[N=256][K](bf16)
// A is f32 (abf=0, cvt on stage) or bf16 (abf=1, direct 16B copies).
// tile 128x128, BK=64, 4 waves each 64x64. LDS XOR-swizzled.
// 1D XCD-paired grid: a row-block's two col-blocks dispatch adjacently on the
// SAME XCD so the A-panel is fetched once per XCD (L2-shared).
// mode 0: C=f32(+bias). mode 1: gate epilogue -> Cbf bf16. mode 2: Cbf bf16(+bias).
// ---------------------------------------------------------------------------
__global__ __launch_bounds__(256)
void gemm_mfma(const void* __restrict__ Av, const void* __restrict__ A2v, int abf,
               const ushort* __restrict__ Wt, const float* __restrict__ bias,
               float* __restrict__ C, ushort* __restrict__ Cbf,
               int M, int K, int lda, int mode,
               const ushort* __restrict__ hn, const ushort* __restrict__ fn,
               const void* __restrict__ prevv, int prevbf)
{
    __shared__ ushort As[128][64];
    __shared__ ushort Bs[128][64];
    const int bid = blockIdx.x;
    const int xcd = bid & 7;
    const int t = bid >> 3;
    const int cb = t & 1;
    const int rowblk = (t >> 1) * 8 + xcd;
    const int row0 = rowblk * 128;
    if (row0 >= M) return;
    const int col0 = cb * 128;
    const int tid = threadIdx.x;
    const int lane = tid & 63;
    const int w = tid >> 6;
    const int wr = (w >> 1) * 64, wc = (w & 1) * 64;
    const int lr = lane & 15, lk = (lane >> 4) * 8;
    f32x4 acc[4][4] = {};

    for (int k0 = 0; k0 < K; k0 += 64) {
        __syncthreads();
        #pragma unroll
        for (int it = 0; it < 4; ++it) {           // stage A: 128x64
            int c = it * 256 + tid;
            int row = c >> 3, col = (c & 7) * 8;
            int gr = row0 + row; if (gr > M - 1) gr = M - 1;
            int kk = k0 + col;
            if (abf) {
                const ushort* Ap = (const ushort*)Av;
                if (A2v != nullptr && kk >= 256) { Ap = (const ushort*)A2v; kk -= 256; }
                *(int4*)&As[row][swz(row, col)] =
                    *(const int4*)&Ap[(size_t)gr * lda + kk];
            } else {
                const float* Ap = (const float*)Av;
                if (A2v != nullptr && kk >= 256) { Ap = (const float*)A2v; kk -= 256; }
                const float* s = &Ap[(size_t)gr * lda + kk];
                float4 v0 = *(const float4*)s;
                float4 v1 = *(const float4*)(s + 4);
                union { ushort u[8]; int4 q; } pk;
                pk.u[0] = f2bf(v0.x); pk.u[1] = f2bf(v0.y); pk.u[2] = f2bf(v0.z); pk.u[3] = f2bf(v0.w);
                pk.u[4] = f2bf(v1.x); pk.u[5] = f2bf(v1.y); pk.u[6] = f2bf(v1.z); pk.u[7] = f2bf(v1.w);
                *(int4*)&As[row][swz(row, col)] = pk.q;
            }
        }
        #pragma unroll
        for (int it = 0; it < 4; ++it) {           // stage B: Wt rows col0..+127
            int c = it * 256 + tid;
            int n = c >> 3, k = (c & 7) * 8;
            *(int4*)&Bs[n][swz(n, k)] = *(const int4*)&Wt[(size_t)(col0 + n) * K + k0 + k];
        }
        __syncthreads();
        #pragma unroll
        for (int ks = 0; ks < 2; ++ks) {
            short8v av[4], bv[4];
            #pragma unroll
            for (int m = 0; m < 4; ++m) {
                int rr = wr + m * 16 + lr;
                av[m] = *(const short8v*)&As[rr][swz(rr, ks * 32 + lk)];
            }
            #pragma unroll
            for (int n = 0; n < 4; ++n) {
                int rr = wc + n * 16 + lr;
                bv[n] = *(const short8v*)&Bs[rr][swz(rr, ks * 32 + lk)];
            }
            #pragma unroll
            for (int m = 0; m < 4; ++m)
                #pragma unroll
                for (int n = 0; n < 4; ++n)
                    acc[m][n] = __builtin_amdgcn_mfma_f32_16x16x32_bf16(av[m], bv[n], acc[m][n], 0, 0, 0);
        }
    }
    const int fr = (lane >> 4) * 4;
    if (mode == 0) {
        #pragma unroll
        for (int n = 0; n < 4; ++n) {
            int col = col0 + wc + n * 16 + lr;
            float bb = bias ? bias[col] : 0.f;
            #pragma unroll
            for (int m = 0; m < 4; ++m) {
                int rbase = row0 + wr + m * 16 + fr;
                #pragma unroll
                for (int r = 0; r < 4; ++r) {
                    int row = rbase + r;
                    if (row < M) C[(size_t)row * HH + col] = acc[m][n][r] + bb;
                }
            }
        }
    } else if (mode == 2) {
        #pragma unroll
        for (int n = 0; n < 4; ++n) {
            int col = col0 + wc + n * 16 + lr;
            float bb = bias ? bias[col] : 0.f;
            #pragma unroll
            for (int m = 0; m < 4; ++m) {
                int rbase = row0 + wr + m * 16 + fr;
                #pragma unroll
                for (int r = 0; r < 4; ++r) {
                    int row = rbase + r;
                    if (row < M) Cbf[(size_t)row * HH + col] = f2bf(acc[m][n][r] + bb);
                }
            }
        }
    } else {
        #pragma unroll
        for (int n = 0; n < 4; ++n) {
            int col = col0 + wc + n * 16 + lr;
            float gb = bias[col];
            #pragma unroll
            for (int m = 0; m < 4; ++m) {
                int rbase = row0 + wr + m * 16 + fr;
                #pragma unroll
                for (int r = 0; r < 4; ++r) {
                    int row = rbase + r;
                    if (row < M) {
                        size_t o = (size_t)row * HH + col;
                        float z = acc[m][n][r] + gb;
                        float s = 1.f / (1.f + expf(-z));
                        float hv = bf2f(hn[o]);
                        float fv = bf2f(fn[o]);
                        float pv = prevbf ? bf2f(((const ushort*)prevv)[o])
                                          : ((const float*)prevv)[o];
                        Cbf[o] = f2bf(s * hv + (1.f - s) * fv + pv);
                    }
                }
            }
        }
    }
}

// ---------------------------------------------------------------------------
// Row L2-normalize (f32 in), emit bf16 hi/lo split (linear layout)
// ---------------------------------------------------------------------------
__global__ __launch_bounds__(256)
void row_norm_hl(const float* __restrict__ h, ushort* __restrict__ xh, ushort* __restrict__ xl)
{
    int n = blockIdx.x, c = threadIdx.x;
    float v = h[(size_t)n * HH + c];
    __shared__ float red[256];
    red[c] = v * v;
    __syncthreads();
    for (int s = 128; s > 0; s >>= 1) {
        if (c < s) red[c] += red[c + s];
        __syncthreads();
    }
    float norm = sqrtf(red[0]);
    float xn = v / (norm + 1e-12f);
    ushort hi = f2bf(xn);
    xh[(size_t)n * HH + c] = hi;
    xl[(size_t)n * HH + c] = f2bf(xn - bf2f(hi));
}

// ---------------------------------------------------------------------------
// top-3 helpers (exact top_k tie-breaking: value desc, index asc)
// ---------------------------------------------------------------------------
__device__ __forceinline__ bool tk_better(float va, int ia, float vb, int ib)
{
    return (va > vb) || (va == vb && ia < ib);
}

__device__ __forceinline__ void ins3(float v, int i,
                                     float& a0, int& b0, float& a1, int& b1,
                                     float& a2, int& b2)
{
    if (tk_better(v, i, a0, b0))      { a2 = a1; b2 = b1; a1 = a0; b1 = b0; a0 = v; b0 = i; }
    else if (tk_better(v, i, a1, b1)) { a2 = a1; b2 = b1; a1 = v;  b1 = i; }
    else if (tk_better(v, i, a2, b2)) { a2 = v;  b2 = i; }
}

__device__ __forceinline__ void merge3(float& v0, float& v1, float& v2,
                                       int& i0, int& i1, int& i2, int off)
{
    float w0 = __shfl_xor(v0, off), w1 = __shfl_xor(v1, off), w2 = __shfl_xor(v2, off);
    int   j0 = __shfl_xor(i0, off), j1 = __shfl_xor(i1, off), j2 = __shfl_xor(i2, off);
    float avv[3] = { v0, v1, v2 }, bvv[3] = { w0, w1, w2 };
    int   aii[3] = { i0, i1, i2 }, bii[3] = { j0, j1, j2 };
    float rv[3]; int ri[3];
    int p = 0, q = 0;
    #pragma unroll
    for (int t = 0; t < 3; ++t) {
        bool takeA = tk_better(avv[p], aii[p], bvv[q], bii[q]);
        rv[t] = takeA ? avv[p] : bvv[q];
        ri[t] = takeA ? aii[p] : bii[q];
        if (takeA) ++p; else ++q;
    }
    v0 = rv[0]; v1 = rv[1]; v2 = rv[2];
    i0 = ri[0]; i1 = ri[1]; i2 = ri[2];
}

// ---------------------------------------------------------------------------
// simtopk (round-8 variant, best measured 306us): reg-A + dbuf-B fused
// sim + top-3. Block = 64 rows of one graph; wave = 16 rows x 128 cols.
// B double-buffered in LDS 32-k chunks, issue-early/write-late (T14).
// XCD-swizzled grid. launch_bounds(256,1).
// ---------------------------------------------------------------------------
__global__ __launch_bounds__(256, 1)
void simtopk(const ushort* __restrict__ xnh, const ushort* __restrict__ xnl,
             int* __restrict__ fsrc)
{
    __shared__ ushort Bs[2][2][128][36];   // [buf][hi/lo][col][k(32)+pad4] = 36 KB
    const int bid = blockIdx.x;
    const int xcd = bid & 7;
    const int rb  = (bid >> 3) & 7;
    const int g   = (bid >> 6) * 8 + xcd;
    if (g >= GG) return;
    const int row0 = rb * 64;
    const int tid  = threadIdx.x;
    const int lane = tid & 63;
    const int w    = tid >> 6;
    const int lr   = lane & 15;
    const int hi4  = lane >> 4;
    const size_t base = (size_t)g * NPGc * HH;

    // ---- A fragments in registers: full K, wave's 16 rows ----
    int arow = row0 + w * 16 + lr; if (arow > NPGc - 1) arow = NPGc - 1;
    const ushort* aph = xnh + base + (size_t)arow * HH + hi4 * 8;
    const ushort* apl = xnl + base + (size_t)arow * HH + hi4 * 8;
    short8v ah[8], al[8];
    #pragma unroll
    for (int kc = 0; kc < 8; ++kc) {
        ah[kc] = *(const short8v*)(aph + kc * 32);
        al[kc] = *(const short8v*)(apl + kc * 32);
    }

    const int scol = tid >> 1;             // 0..127
    const int sq   = (tid & 1) * 2;        // granule 0 or 2

    float tv0[4], tv1[4], tv2[4];
    int   ti0[4], ti1[4], ti2[4];
    #pragma unroll
    for (int r = 0; r < 4; ++r) {
        tv0[r] = tv1[r] = tv2[r] = -2.f;
        ti0[r] = ti1[r] = ti2[r] = 0x7fffffff;
    }

    for (int ct = 0; ct < 4; ++ct) {
        const int col0 = ct * 128;
        int gcol = col0 + scol; if (gcol > NPGc - 1) gcol = NPGc - 1;
        const ushort* sph = xnh + base + (size_t)gcol * HH + sq * 8;
        const ushort* spl = xnl + base + (size_t)gcol * HH + sq * 8;

        {
            int4 h0 = *(const int4*)(sph);
            int4 h1 = *(const int4*)(sph + 8);
            int4 l0 = *(const int4*)(spl);
            int4 l1 = *(const int4*)(spl + 8);
            *(int4*)&Bs[0][0][scol][sq * 8]     = h0;
            *(int4*)&Bs[0][0][scol][sq * 8 + 8] = h1;
            *(int4*)&Bs[0][1][scol][sq * 8]     = l0;
            *(int4*)&Bs[0][1][scol][sq * 8 + 8] = l1;
        }
        __syncthreads();

        f32x4 acc[8] = {};
        #pragma unroll
        for (int kc = 0; kc < 8; ++kc) {
            const int cur = kc & 1, nxt = cur ^ 1;
            int4 h0, h1, l0, l1;
            if (kc < 7) {
                const ushort* nh = sph + (kc + 1) * 32;
                const ushort* nl = spl + (kc + 1) * 32;
                h0 = *(const int4*)(nh);
                h1 = *(const int4*)(nh + 8);
                l0 = *(const int4*)(nl);
                l1 = *(const int4*)(nl + 8);
            }
            short8v bh[8], bl[8];
            #pragma unroll
            for (int n = 0; n < 8; ++n) {
                int rr = n * 16 + lr;
                bh[n] = *(const short8v*)&Bs[cur][0][rr][hi4 * 8];
                bl[n] = *(const short8v*)&Bs[cur][1][rr][hi4 * 8];
            }
            #pragma unroll
            for (int n = 0; n < 8; ++n) {
                acc[n] = __builtin_amdgcn_mfma_f32_16x16x32_bf16(ah[kc], bh[n], acc[n], 0, 0, 0);
                acc[n] = __builtin_amdgcn_mfma_f32_16x16x32_bf16(ah[kc], bl[n], acc[n], 0, 0, 0);
                acc[n] = __builtin_amdgcn_mfma_f32_16x16x32_bf16(al[kc], bh[n], acc[n], 0, 0, 0);
            }
            if (kc < 7) {
                *(int4*)&Bs[nxt][0][scol][sq * 8]     = h0;
                *(int4*)&Bs[nxt][0][scol][sq * 8 + 8] = h1;
                *(int4*)&Bs[nxt][1][scol][sq * 8]     = l0;
                *(int4*)&Bs[nxt][1][scol][sq * 8 + 8] = l1;
            }
            __syncthreads();
        }

        #pragma unroll
        for (int r = 0; r < 4; ++r) {
            float a0 = tv0[r], a1 = tv1[r], a2 = tv2[r];
            int   b0 = ti0[r], b1 = ti1[r], b2 = ti2[r];
            #pragma unroll
            for (int n = 0; n < 8; ++n) {
                int col = col0 + n * 16 + lr;
                if (col < NPGc)
                    ins3(acc[n][r], col, a0, b0, a1, b1, a2, b2);
            }
            tv0[r] = a0; tv1[r] = a1; tv2[r] = a2;
            ti0[r] = b0; ti1[r] = b1; ti2[r] = b2;
        }
    }

    #pragma unroll
    for (int r = 0; r < 4; ++r) {
        float a0 = tv0[r], a1 = tv1[r], a2 = tv2[r];
        int   b0 = ti0[r], b1 = ti1[r], b2 = ti2[r];
        #pragma unroll
        for (int off = 1; off <= 8; off <<= 1)
            merge3(a0, a1, a2, b0, b1, b2, off);
        if (lr == 0) {
            int row = row0 + w * 16 + hi4 * 4 + r;
            if (row < NPGc) {
                int rg = g * NPGc + row;
                fsrc[rg * 3 + 0] = g * NPGc + b0;
                fsrc[rg * 3 + 1] = g * NPGc + b1;
                fsrc[rg * 3 + 2] = g * NPGc + b2;
            }
        }
    }
}

// ---------------------------------------------------------------------------
// CSR build
// ---------------------------------------------------------------------------
__global__ void hist_kernel(const int* __restrict__ dst, int* __restrict__ cnt, int nE)
{
    int e = blockIdx.x * 256 + threadIdx.x;
    if (e < nE) atomicAdd(&cnt[dst[e]], 1);
}

__global__ void scan1_kernel(const int* __restrict__ in, int* __restrict__ out,
                             int* __restrict__ bsum, int n)
{
    __shared__ int sh[256];
    int t = threadIdx.x;
    int i = blockIdx.x * 256 + t;
    int v = (i < n) ? in[i] : 0;
    sh[t] = v;
    __syncthreads();
    for (int s = 1; s < 256; s <<= 1) {
        int tv = (t >= s) ? sh[t - s] : 0;
        __syncthreads();
        sh[t] += tv;
        __syncthreads();
    }
    if (i < n) out[i] = sh[t] - v;  // exclusive
    if (t == 255) bsum[blockIdx.x] = sh[255];
}

__global__ void scan2_kernel(int* __restrict__ bsum, int nb)
{
    __shared__ int sh[256];
    int t = threadIdx.x;
    int v = (t < nb) ? bsum[t] : 0;
    sh[t] = v;
    __syncthreads();
    for (int s = 1; s < 256; s <<= 1) {
        int tv = (t >= s) ? sh[t - s] : 0;
        __syncthreads();
        sh[t] += tv;
        __syncthreads();
    }
    if (t < nb) bsum[t] = sh[t] - v;
}

__global__ void scan3_kernel(int* __restrict__ out, const int* __restrict__ bsum, int n)
{
    int i = blockIdx.x * 256 + threadIdx.x;
    if (i < n) out[i] += bsum[blockIdx.x];
}

__global__ void fill_kernel(const int* __restrict__ src, const int* __restrict__ dst,
                            const int* __restrict__ row_ptr, int* __restrict__ cursor,
                            int* __restrict__ sorted_src, int nE)
{
    int e = blockIdx.x * 256 + threadIdx.x;
    if (e < nE) {
        int d = dst[e];
        int pos = row_ptr[d] + atomicAdd(&cursor[d], 1);
        sorted_src[pos] = src[e];
    }
}

__global__ void dinv_kernel(const int* __restrict__ cnt, float* __restrict__ dinv, int n)
{
    int i = blockIdx.x * 256 + threadIdx.x;
    if (i < n) dinv[i] = rsqrtf((float)cnt[i] + 1.0f);
}

// ---------------------------------------------------------------------------
// GCN gather (bf16 messages in, bf16 out, XCD-bijective swizzle)
// ---------------------------------------------------------------------------
__global__ __launch_bounds__(256)
void gcn_gather(const ushort* __restrict__ m, const int* __restrict__ row_ptr,
                const int* __restrict__ cnt, const int* __restrict__ srcs,
                const float* __restrict__ dinv, const float* __restrict__ bias,
                ushort* __restrict__ out)
{
    int bid = blockIdx.x;
    int xcd = bid & 7, idx = bid >> 3;
    int g = xcd + 8 * (idx / NPGc);
    if (g >= GG) return;
    int n = g * NPGc + (idx % NPGc);
    int c = threadIdx.x;
    float dn = dinv[n];
    float acc = bf2f(m[(size_t)n * HH + c]) * dn;
    int s0 = row_ptr[n], e0 = s0 + cnt[n];
    for (int e = s0; e < e0; ++e) {
        int s = srcs[e];
        acc += bf2f(m[(size_t)s * HH + c]) * dinv[s];
    }
    out[(size_t)n * HH + c] = f2bf(acc * dn + bias[c]);
}

__global__ __launch_bounds__(256)
void fgcn_gather(const ushort* __restrict__ m, const int* __restrict__ fsrc,
                 const float* __restrict__ bias, ushort* __restrict__ out)
{
    int bid = blockIdx.x;
    int xcd = bid & 7, idx = bid >> 3;
    int g = xcd + 8 * (idx / NPGc);
    if (g >= GG) return;
    int n = g * NPGc + (idx % NPGc);
    int c = threadIdx.x;
    int s0 = fsrc[n * 3], s1 = fsrc[n * 3 + 1], s2 = fsrc[n * 3 + 2];
    float acc = bf2f(m[(size_t)n * HH + c]) + bf2f(m[(size_t)s0 * HH + c])
              + bf2f(m[(size_t)s1 * HH + c]) + bf2f(m[(size_t)s2 * HH + c]);
    out[(size_t)n * HH + c] = f2bf(0.25f * acc + bias[c]);
}

// ---------------------------------------------------------------------------
// GraphNorm: chunked partial stats -> tiny reduce (MM = mean*ms, RS = rstd)
// -> apply reads 2 floats/thread (fixes r12's 800MB partial re-read).
// ---------------------------------------------------------------------------
__global__ __launch_bounds__(256)
void norm_stats(const ushort* __restrict__ x, float* __restrict__ S1p, float* __restrict__ S2p)
{
    int g = blockIdx.x, chunk = blockIdx.y, c = threadIdx.x;
    int r0 = chunk * 63, r1 = min(r0 + 63, NPGc);
    float s1 = 0.f, s2 = 0.f;
    for (int r = r0; r < r1; ++r) {
        float v = bf2f(x[((size_t)(g * NPGc + r)) * HH + c]);
        s1 += v; s2 += v * v;
    }
    size_t o = ((size_t)(g * 8 + chunk)) * HH + c;
    S1p[o] = s1;
    S2p[o] = s2;
}

__global__ __launch_bounds__(256)
void norm_reduce(const float* __restrict__ S1p, const float* __restrict__ S2p,
                 const float* __restrict__ ms, float* __restrict__ MM, float* __restrict__ RS)
{
    int g = blockIdx.x, c = threadIdx.x;
    float s1 = 0.f, s2 = 0.f;
    #pragma unroll
    for (int j = 0; j < 8; ++j) {
        size_t po = ((size_t)(g * 8 + j)) * HH + c;
        s1 += S1p[po];
        s2 += S2p[po];
    }
    float mean = s1 / (float)NPGc;
    float mm = mean * ms[c];
    float var = s2 / (float)NPGc - 2.f * mm * mean + mm * mm;
    MM[g * HH + c] = mm;
    RS[g * HH + c] = rsqrtf(var + 1e-5f);
}

__global__ __launch_bounds__(256)
void norm_apply(ushort* __restrict__ x, const float* __restrict__ MM, const float* __restrict__ RS,
                const float* __restrict__ w, const float* __restrict__ b)
{
    int n = blockIdx.x, c = threadIdx.x;
    int g = n / NPGc;
    size_t o = (size_t)n * HH + c;
    float v = bf2f(x[o]);
    float outv = w[c] * (v - MM[g * HH + c]) * RS[g * HH + c] + b[c];
    x[o] = f2bf(outv > 0.f ? outv : 0.01f * outv);
}

// ---------------------------------------------------------------------------
// Pool: gf[g] = (sum H0 + 2*sum H1) / 500   (all_x[-1]==all_x[1] quirk)
// ---------------------------------------------------------------------------
__global__ __launch_bounds__(256)
void pool_kernel(const ushort* __restrict__ X0, const ushort* __restrict__ X1,
                 float* __restrict__ out)
{
    int g = blockIdx.x, c = threadIdx.x;
    float s0 = 0.f, s1 = 0.f;
    for (int r = 0; r < NPGc; ++r) {
        size_t o = ((size_t)(g * NPGc + r)) * HH + c;
        s0 += bf2f(X0[o]);
        s1 += bf2f(X1[o]);
    }
    out[g * HH + c] = (s0 + 2.f * s1) / (float)NPGc;
}

__global__ void sentinel_kernel(float* out, int n)
{
    int i = blockIdx.x * 256 + threadIdx.x;
    if (i < n) out[i] = 12345.0f;
}

// ---------------------------------------------------------------------------
extern "C" void kernel_launch(void* const* d_in, const int* in_sizes, int n_in,
                              void* d_out, int out_size, void* d_ws, size_t ws_size,
                              hipStream_t stream)
{
    const float* x       = (const float*)d_in[0];
    const int* edge_idx  = (const int*)d_in[1];
    const float* emb_W   = (const float*)d_in[3];
    const float* emb_b   = (const float*)d_in[4];
    const float* conv_W  = (const float*)d_in[5];
    const float* conv_b  = (const float*)d_in[6];
    const float* fconv_W = (const float*)d_in[7];
    const float* fconv_b = (const float*)d_in[8];
    const float* norm_w  = (const float*)d_in[9];
    const float* norm_b  = (const float*)d_in[10];
    const float* norm_ms = (const float*)d_in[11];
    const float* fnorm_w = (const float*)d_in[12];
    const float* fnorm_b = (const float*)d_in[13];
    const float* fnorm_ms= (const float*)d_in[14];
    const float* gate_W  = (const float*)d_in[15];
    const float* gate_b  = (const float*)d_in[16];

    const int E = in_sizes[1] / 2;
    const int* esrc = edge_idx;
    const int* edst = edge_idx + E;

    const size_t NHf = (size_t)NN * HH;           // 12.8M elements
    char* p = (char*)d_ws;
    auto alloc = [&](size_t bytes) { char* r = p; p += (bytes + 255) & ~(size_t)255; return r; };
    float*  B0 = (float*)alloc(NHf * 4);          // emb out (f32, feeds knn)
    ushort* Mr = (ushort*)alloc(NHf * 2);         // messages
    ushort* Ar = (ushort*)alloc(NHf * 2);         // h-road act
    ushort* Br = (ushort*)alloc(NHf * 2);         // f-road act
    ushort* H0 = (ushort*)alloc(NHf * 2);         // layer0 out
    ushort* H1 = (ushort*)alloc(NHf * 2);         // layer1 out
    ushort* xnh = Mr;                             // knn operands overlay Mr/Ar
    ushort* xnl = Ar;
    int* sorted_src = (int*)alloc((size_t)E * 4);
    int* row_ptr    = (int*)alloc((size_t)NN * 4);
    int* deg_cnt    = (int*)alloc((size_t)NN * 4);
    int* cursor     = (int*)alloc((size_t)NN * 4);
    float* dinv     = (float*)alloc((size_t)NN * 4);
    int* fsrc       = (int*)alloc((size_t)NN * 3 * 4);
    float* S1p      = (float*)alloc((size_t)GG * 8 * HH * 4);
    float* S2p      = (float*)alloc((size_t)GG * 8 * HH * 4);
    float* MM       = (float*)alloc((size_t)GG * HH * 4);
    float* RS       = (float*)alloc((size_t)GG * HH * 4);
    int* bsum       = (int*)alloc(1024);
    ushort* wts     = (ushort*)alloc((size_t)425984 * 2);  // all W^T bf16
    size_t needed = (size_t)(p - (char*)d_ws);
    if (ws_size < needed) {
        sentinel_kernel<<<(out_size + 255) / 256, 256, 0, stream>>>((float*)d_out, out_size);
        return;
    }
    ushort* embWt   = wts;                    // [256][128]
    ushort* convWt0 = wts + 32768;            // [256][256]
    ushort* convWt1 = wts + 98304;
    ushort* fconvWt0 = wts + 163840;
    ushort* fconvWt1 = wts + 229376;
    ushort* gateWt  = wts + 294912;           // [256][512]

    const int nScanB = (NN + 255) / 256;  // 196
    const int gatherGrid = 8 * 13 * NPGc; // 52000 (XCD-bijective, skip g>=100)
    const int gemmGrid = 8 * 49 * 2;      // 784 (XCD-paired rowblk/colblk)

    hipMemsetAsync(deg_cnt, 0, (size_t)NN * 4, stream);
    hipMemsetAsync(cursor, 0, (size_t)NN * 4, stream);

    // 0. all weight transposes+cvt in one launch
    wcvt_all<<<1664, 256, 0, stream>>>(emb_W, conv_W, fconv_W, gate_W, wts);

    // 1. embedding: h0 = x @ emb_W + emb_b -> B0 (f32)
    gemm_mfma<<<gemmGrid, 256, 0, stream>>>(x, nullptr, 0, embWt, emb_b, B0, nullptr,
                                            NN, IND, IND, 0, nullptr, nullptr, nullptr, 0);

    // 2. CSR of edge_index by dst
    hist_kernel<<<(E + 255) / 256, 256, 0, stream>>>(edst, deg_cnt, E);
    scan1_kernel<<<nScanB, 256, 0, stream>>>(deg_cnt, row_ptr, bsum, NN);
    scan2_kernel<<<1, 256, 0, stream>>>(bsum, nScanB);
    scan3_kernel<<<nScanB, 256, 0, stream>>>(row_ptr, bsum, NN);
    fill_kernel<<<(E + 255) / 256, 256, 0, stream>>>(esrc, edst, row_ptr, cursor, sorted_src, E);
    dinv_kernel<<<(NN + 255) / 256, 256, 0, stream>>>(deg_cnt, dinv, NN);

    // 3. knn graph from h0 (hi/lo split, fused sim+topk)
    row_norm_hl<<<NN, 256, 0, stream>>>(B0, xnh, xnl);
    simtopk<<<832, 256, 0, stream>>>(xnh, xnl, fsrc);

    // 4. layers (bf16 activations throughout)
    dim3 ngrid(GG, 8);
    const void* hptr = (const void*)B0;   // prev/conv-input; f32 for layer 0
    int habf = 0;
    ushort* Hout[2] = { H0, H1 };
    for (int i = 0; i < 2; ++i) {
        const ushort* Wc = (i == 0) ? convWt0 : convWt1;
        const ushort* Wf = (i == 0) ? fconvWt0 : fconvWt1;
        const float* bc  = conv_b  + (size_t)i * HH;
        const float* bf  = fconv_b + (size_t)i * HH;
        // h-road conv -> bf16 messages
        gemm_mfma<<<gemmGrid, 256, 0, stream>>>(hptr, nullptr, habf, Wc, nullptr, nullptr, Mr,
                                                NN, HH, HH, 2, nullptr, nullptr, nullptr, 0);
        gcn_gather<<<gatherGrid, 256, 0, stream>>>(Mr, row_ptr, deg_cnt, sorted_src,
                                                   dinv, bc, Ar);
        norm_stats<<<ngrid, 256, 0, stream>>>(Ar, S1p, S2p);
        norm_reduce<<<GG, 256, 0, stream>>>(S1p, S2p, norm_ms + i * HH, MM, RS);
        norm_apply<<<NN, 256, 0, stream>>>(Ar, MM, RS, norm_w + i * HH, norm_b + i * HH);
        // f-road conv (knn graph) -> bf16 messages
        gemm_mfma<<<gemmGrid, 256, 0, stream>>>(Ar, nullptr, 1, Wf, nullptr, nullptr, Mr,
                                                NN, HH, HH, 2, nullptr, nullptr, nullptr, 0);
        fgcn_gather<<<gatherGrid, 256, 0, stream>>>(Mr, fsrc, bf, Br);
        norm_stats<<<ngrid, 256, 0, stream>>>(Br, S1p, S2p);
        norm_reduce<<<GG, 256, 0, stream>>>(S1p, S2p, fnorm_ms + i * HH, MM, RS);
        norm_apply<<<NN, 256, 0, stream>>>(Br, MM, RS, fnorm_w + i * HH, fnorm_b + i * HH);
        // gate + combine -> bf16 H_i
        gemm_mfma<<<gemmGrid, 256, 0, stream>>>(Ar, Br, 1, gateWt, gate_b, nullptr, Hout[i],
                                                NN, 2 * HH, HH, 1, Ar, Br, hptr, habf);
        hptr = (const void*)Hout[i];
        habf = 1;
    }
    // all_x[0]=H0, all_x[1]=H1: gf = (sum H0 + 2*sum H1)/500
    pool_kernel<<<GG, 256, 0, stream>>>(H0, H1, (float*)d_out);
}

// Round 14
// 1249.384 us; speedup vs baseline: 1.1871x; 1.0117x over previous
//
#include <hip/hip_runtime.h>
#include <math.h>

#define NN 50000      // nodes
#define GG 100        // graphs
#define NPGc 500      // nodes per graph
#define HH 256        // hidden
#define IND 128       // input dim

typedef __attribute__((ext_vector_type(8))) short short8v;  // 8 bf16
typedef __attribute__((ext_vector_type(4))) float f32x4;

__device__ __forceinline__ ushort f2bf(float f) {
    union { float f; unsigned u; } v; v.f = f;
    unsigned r = (v.u + 0x7fffu + ((v.u >> 16) & 1u)) >> 16;  // RNE
    return (ushort)r;
}
__device__ __forceinline__ float bf2f(ushort h) {
    union { unsigned u; float f; } v; v.u = ((unsigned)h) << 16;
    return v.f;
}
__device__ __forceinline__ float lrelu(float v) { return v > 0.f ? v : 0.01f * v; }

// LDS ushort-index swizzle: XOR 16B-granule bits with row&7 (T2)
__device__ __forceinline__ int swz(int row, int kidx) { return kidx ^ ((row & 7) << 3); }

// ---------------------------------------------------------------------------
// All weight transposes+converts in ONE launch. dst layout (ushort elems):
// [0,32768) embWt [256][128] | [32768,98304) convWt0 | [98304,163840) convWt1
// [163840,229376) fconvWt0 | [229376,294912) fconvWt1 | [294912,425984) gateWt
// ---------------------------------------------------------------------------
__global__ void wcvt_all(const float* __restrict__ emb_W, const float* __restrict__ conv_W,
                         const float* __restrict__ fconv_W, const float* __restrict__ gate_W,
                         ushort* __restrict__ dst)
{
    int i = blockIdx.x * 256 + threadIdx.x;
    if (i >= 425984) return;
    float v;
    if (i < 32768)       { int n = i >> 7, k = i & 127;              v = emb_W[(size_t)k * 256 + n]; }
    else if (i < 98304)  { int j = i - 32768;  int n = j >> 8, k = j & 255; v = conv_W[(size_t)k * 256 + n]; }
    else if (i < 163840) { int j = i - 98304;  int n = j >> 8, k = j & 255; v = conv_W[65536 + (size_t)k * 256 + n]; }
    else if (i < 229376) { int j = i - 163840; int n = j >> 8, k = j & 255; v = fconv_W[(size_t)k * 256 + n]; }
    else if (i < 294912) { int j = i - 229376; int n = j >> 8, k = j & 255; v = fconv_W[65536 + (size_t)k * 256 + n]; }
    else                 { int j = i - 294912; int n = j >> 9, k = j & 511; v = gate_W[(size_t)k * 256 + n]; }
    dst[i] = f2bf(v);
}

// ---------------------------------------------------------------------------
// bf16 MFMA GEMM with FUSED GraphNorm-apply on operands.
// C[M x 256] = normA(A)[M x K] @ Wt[N=256][K](bf16)
// A f32 (abf=0, cvt on stage, never normed) or bf16 (abf=1).
// If MMa != null: A-stage applies lrelu(nwa*(v-MMa)*RSa+nba) (road-h params);
// A2 side likewise with the b-set (gate concat, road-f params).
// mode 0: C=f32(+bias). mode 2: Cbf=bf16(+bias).
// mode 1 (gate): z=acc+bias; s=sigmoid(z); out = s*normA(A)+ (1-s)*normB(A2)
//                + prev; epilogue re-reads A/A2 raw and normalizes on the fly.
// 1D XCD-paired grid (row-block's two col-blocks adjacent on same XCD).
// ---------------------------------------------------------------------------
__global__ __launch_bounds__(256)
void gemm_mfma(const void* __restrict__ Av, const void* __restrict__ A2v, int abf,
               const ushort* __restrict__ Wt, const float* __restrict__ bias,
               float* __restrict__ C, ushort* __restrict__ Cbf,
               int M, int K, int lda, int mode,
               const void* __restrict__ prevv, int prevbf,
               const float* __restrict__ MMa, const float* __restrict__ RSa,
               const float* __restrict__ nwa, const float* __restrict__ nba,
               const float* __restrict__ MMb, const float* __restrict__ RSb,
               const float* __restrict__ nwb, const float* __restrict__ nbb)
{
    __shared__ ushort As[128][64];
    __shared__ ushort Bs[128][64];
    const int bid = blockIdx.x;
    const int xcd = bid & 7;
    const int t = bid >> 3;
    const int cb = t & 1;
    const int rowblk = (t >> 1) * 8 + xcd;
    const int row0 = rowblk * 128;
    if (row0 >= M) return;
    const int col0 = cb * 128;
    const int tid = threadIdx.x;
    const int lane = tid & 63;
    const int w = tid >> 6;
    const int wr = (w >> 1) * 64, wc = (w & 1) * 64;
    const int lr = lane & 15, lk = (lane >> 4) * 8;
    f32x4 acc[4][4] = {};

    for (int k0 = 0; k0 < K; k0 += 64) {
        __syncthreads();
        #pragma unroll
        for (int it = 0; it < 4; ++it) {           // stage A: 128x64
            int c = it * 256 + tid;
            int row = c >> 3, col = (c & 7) * 8;
            int gr = row0 + row; if (gr > M - 1) gr = M - 1;
            int kk = k0 + col;
            if (abf) {
                const ushort* Ap = (const ushort*)Av;
                const float *MMp = MMa, *RSp = RSa, *wp = nwa, *bp = nba;
                if (A2v != nullptr && kk >= 256) {
                    Ap = (const ushort*)A2v; kk -= 256;
                    MMp = MMb; RSp = RSb; wp = nwb; bp = nbb;
                }
                int4 raw = *(const int4*)&Ap[(size_t)gr * lda + kk];
                if (MMp != nullptr) {
                    int g = gr / NPGc;
                    const ushort* rp = (const ushort*)&raw;
                    float4 mm0 = *(const float4*)&MMp[(size_t)g * HH + kk];
                    float4 mm1 = *(const float4*)&MMp[(size_t)g * HH + kk + 4];
                    float4 rs0 = *(const float4*)&RSp[(size_t)g * HH + kk];
                    float4 rs1 = *(const float4*)&RSp[(size_t)g * HH + kk + 4];
                    float4 w0 = *(const float4*)&wp[kk];
                    float4 w1 = *(const float4*)&wp[kk + 4];
                    float4 b0 = *(const float4*)&bp[kk];
                    float4 b1 = *(const float4*)&bp[kk + 4];
                    float mms[8] = { mm0.x, mm0.y, mm0.z, mm0.w, mm1.x, mm1.y, mm1.z, mm1.w };
                    float rss[8] = { rs0.x, rs0.y, rs0.z, rs0.w, rs1.x, rs1.y, rs1.z, rs1.w };
                    float wss[8] = { w0.x, w0.y, w0.z, w0.w, w1.x, w1.y, w1.z, w1.w };
                    float bss[8] = { b0.x, b0.y, b0.z, b0.w, b1.x, b1.y, b1.z, b1.w };
                    union { ushort u[8]; int4 q; } pk;
                    #pragma unroll
                    for (int j = 0; j < 8; ++j) {
                        float v = bf2f(rp[j]);
                        pk.u[j] = f2bf(lrelu(wss[j] * (v - mms[j]) * rss[j] + bss[j]));
                    }
                    *(int4*)&As[row][swz(row, col)] = pk.q;
                } else {
                    *(int4*)&As[row][swz(row, col)] = raw;
                }
            } else {
                const float* Ap = (const float*)Av;
                if (A2v != nullptr && kk >= 256) { Ap = (const float*)A2v; kk -= 256; }
                const float* s = &Ap[(size_t)gr * lda + kk];
                float4 v0 = *(const float4*)s;
                float4 v1 = *(const float4*)(s + 4);
                union { ushort u[8]; int4 q; } pk;
                pk.u[0] = f2bf(v0.x); pk.u[1] = f2bf(v0.y); pk.u[2] = f2bf(v0.z); pk.u[3] = f2bf(v0.w);
                pk.u[4] = f2bf(v1.x); pk.u[5] = f2bf(v1.y); pk.u[6] = f2bf(v1.z); pk.u[7] = f2bf(v1.w);
                *(int4*)&As[row][swz(row, col)] = pk.q;
            }
        }
        #pragma unroll
        for (int it = 0; it < 4; ++it) {           // stage B: Wt rows col0..+127
            int c = it * 256 + tid;
            int n = c >> 3, k = (c & 7) * 8;
            *(int4*)&Bs[n][swz(n, k)] = *(const int4*)&Wt[(size_t)(col0 + n) * K + k0 + k];
        }
        __syncthreads();
        #pragma unroll
        for (int ks = 0; ks < 2; ++ks) {
            short8v av[4], bv[4];
            #pragma unroll
            for (int m = 0; m < 4; ++m) {
                int rr = wr + m * 16 + lr;
                av[m] = *(const short8v*)&As[rr][swz(rr, ks * 32 + lk)];
            }
            #pragma unroll
            for (int n = 0; n < 4; ++n) {
                int rr = wc + n * 16 + lr;
                bv[n] = *(const short8v*)&Bs[rr][swz(rr, ks * 32 + lk)];
            }
            #pragma unroll
            for (int m = 0; m < 4; ++m)
                #pragma unroll
                for (int n = 0; n < 4; ++n)
                    acc[m][n] = __builtin_amdgcn_mfma_f32_16x16x32_bf16(av[m], bv[n], acc[m][n], 0, 0, 0);
        }
    }
    const int fr = (lane >> 4) * 4;
    if (mode == 0) {
        #pragma unroll
        for (int n = 0; n < 4; ++n) {
            int col = col0 + wc + n * 16 + lr;
            float bb = bias ? bias[col] : 0.f;
            #pragma unroll
            for (int m = 0; m < 4; ++m) {
                int rbase = row0 + wr + m * 16 + fr;
                #pragma unroll
                for (int r = 0; r < 4; ++r) {
                    int row = rbase + r;
                    if (row < M) C[(size_t)row * HH + col] = acc[m][n][r] + bb;
                }
            }
        }
    } else if (mode == 2) {
        #pragma unroll
        for (int n = 0; n < 4; ++n) {
            int col = col0 + wc + n * 16 + lr;
            float bb = bias ? bias[col] : 0.f;
            #pragma unroll
            for (int m = 0; m < 4; ++m) {
                int rbase = row0 + wr + m * 16 + fr;
                #pragma unroll
                for (int r = 0; r < 4; ++r) {
                    int row = rbase + r;
                    if (row < M) Cbf[(size_t)row * HH + col] = f2bf(acc[m][n][r] + bb);
                }
            }
        }
    } else {
        const ushort* hraw = (const ushort*)Av;
        const ushort* fraw = (const ushort*)A2v;
        #pragma unroll
        for (int n = 0; n < 4; ++n) {
            int col = col0 + wc + n * 16 + lr;
            float gb = bias[col];
            float wh = nwa[col], bh = nba[col];
            float wf = nwb[col], bf2 = nbb[col];
            #pragma unroll
            for (int m = 0; m < 4; ++m) {
                int rbase = row0 + wr + m * 16 + fr;
                #pragma unroll
                for (int r = 0; r < 4; ++r) {
                    int row = rbase + r;
                    if (row < M) {
                        size_t o = (size_t)row * HH + col;
                        int g = row / NPGc;
                        size_t go = (size_t)g * HH + col;
                        float z = acc[m][n][r] + gb;
                        float s = 1.f / (1.f + expf(-z));
                        float hv = lrelu(wh * (bf2f(hraw[o]) - MMa[go]) * RSa[go] + bh);
                        float fv = lrelu(wf * (bf2f(fraw[o]) - MMb[go]) * RSb[go] + bf2);
                        float pv = prevbf ? bf2f(((const ushort*)prevv)[o])
                                          : ((const float*)prevv)[o];
                        Cbf[o] = f2bf(s * hv + (1.f - s) * fv + pv);
                    }
                }
            }
        }
    }
}

// ---------------------------------------------------------------------------
// Row L2-normalize (f32 in), emit bf16 hi/lo split (linear layout)
// ---------------------------------------------------------------------------
__global__ __launch_bounds__(256)
void row_norm_hl(const float* __restrict__ h, ushort* __restrict__ xh, ushort* __restrict__ xl)
{
    int n = blockIdx.x, c = threadIdx.x;
    float v = h[(size_t)n * HH + c];
    __shared__ float red[256];
    red[c] = v * v;
    __syncthreads();
    for (int s = 128; s > 0; s >>= 1) {
        if (c < s) red[c] += red[c + s];
        __syncthreads();
    }
    float norm = sqrtf(red[0]);
    float xn = v / (norm + 1e-12f);
    ushort hi = f2bf(xn);
    xh[(size_t)n * HH + c] = hi;
    xl[(size_t)n * HH + c] = f2bf(xn - bf2f(hi));
}

// ---------------------------------------------------------------------------
// top-3 helpers (exact top_k tie-breaking: value desc, index asc)
// ---------------------------------------------------------------------------
__device__ __forceinline__ bool tk_better(float va, int ia, float vb, int ib)
{
    return (va > vb) || (va == vb && ia < ib);
}

__device__ __forceinline__ void ins3(float v, int i,
                                     float& a0, int& b0, float& a1, int& b1,
                                     float& a2, int& b2)
{
    if (tk_better(v, i, a0, b0))      { a2 = a1; b2 = b1; a1 = a0; b1 = b0; a0 = v; b0 = i; }
    else if (tk_better(v, i, a1, b1)) { a2 = a1; b2 = b1; a1 = v;  b1 = i; }
    else if (tk_better(v, i, a2, b2)) { a2 = v;  b2 = i; }
}

__device__ __forceinline__ void merge3(float& v0, float& v1, float& v2,
                                       int& i0, int& i1, int& i2, int off)
{
    float w0 = __shfl_xor(v0, off), w1 = __shfl_xor(v1, off), w2 = __shfl_xor(v2, off);
    int   j0 = __shfl_xor(i0, off), j1 = __shfl_xor(i1, off), j2 = __shfl_xor(i2, off);
    float avv[3] = { v0, v1, v2 }, bvv[3] = { w0, w1, w2 };
    int   aii[3] = { i0, i1, i2 }, bii[3] = { j0, j1, j2 };
    float rv[3]; int ri[3];
    int p = 0, q = 0;
    #pragma unroll
    for (int t = 0; t < 3; ++t) {
        bool takeA = tk_better(avv[p], aii[p], bvv[q], bii[q]);
        rv[t] = takeA ? avv[p] : bvv[q];
        ri[t] = takeA ? aii[p] : bii[q];
        if (takeA) ++p; else ++q;
    }
    v0 = rv[0]; v1 = rv[1]; v2 = rv[2];
    i0 = ri[0]; i1 = ri[1]; i2 = ri[2];
}

// ---------------------------------------------------------------------------
// simtopk (round-8 variant, measured floor 306us): reg-A + dbuf-B fused
// sim + top-3. Block = 64 rows of one graph; wave = 16 rows x 128 cols.
// ---------------------------------------------------------------------------
__global__ __launch_bounds__(256, 1)
void simtopk(const ushort* __restrict__ xnh, const ushort* __restrict__ xnl,
             int* __restrict__ fsrc)
{
    __shared__ ushort Bs[2][2][128][36];   // [buf][hi/lo][col][k(32)+pad4] = 36 KB
    const int bid = blockIdx.x;
    const int xcd = bid & 7;
    const int rb  = (bid >> 3) & 7;
    const int g   = (bid >> 6) * 8 + xcd;
    if (g >= GG) return;
    const int row0 = rb * 64;
    const int tid  = threadIdx.x;
    const int lane = tid & 63;
    const int w    = tid >> 6;
    const int lr   = lane & 15;
    const int hi4  = lane >> 4;
    const size_t base = (size_t)g * NPGc * HH;

    int arow = row0 + w * 16 + lr; if (arow > NPGc - 1) arow = NPGc - 1;
    const ushort* aph = xnh + base + (size_t)arow * HH + hi4 * 8;
    const ushort* apl = xnl + base + (size_t)arow * HH + hi4 * 8;
    short8v ah[8], al[8];
    #pragma unroll
    for (int kc = 0; kc < 8; ++kc) {
        ah[kc] = *(const short8v*)(aph + kc * 32);
        al[kc] = *(const short8v*)(apl + kc * 32);
    }

    const int scol = tid >> 1;
    const int sq   = (tid & 1) * 2;

    float tv0[4], tv1[4], tv2[4];
    int   ti0[4], ti1[4], ti2[4];
    #pragma unroll
    for (int r = 0; r < 4; ++r) {
        tv0[r] = tv1[r] = tv2[r] = -2.f;
        ti0[r] = ti1[r] = ti2[r] = 0x7fffffff;
    }

    for (int ct = 0; ct < 4; ++ct) {
        const int col0 = ct * 128;
        int gcol = col0 + scol; if (gcol > NPGc - 1) gcol = NPGc - 1;
        const ushort* sph = xnh + base + (size_t)gcol * HH + sq * 8;
        const ushort* spl = xnl + base + (size_t)gcol * HH + sq * 8;

        {
            int4 h0 = *(const int4*)(sph);
            int4 h1 = *(const int4*)(sph + 8);
            int4 l0 = *(const int4*)(spl);
            int4 l1 = *(const int4*)(spl + 8);
            *(int4*)&Bs[0][0][scol][sq * 8]     = h0;
            *(int4*)&Bs[0][0][scol][sq * 8 + 8] = h1;
            *(int4*)&Bs[0][1][scol][sq * 8]     = l0;
            *(int4*)&Bs[0][1][scol][sq * 8 + 8] = l1;
        }
        __syncthreads();

        f32x4 acc[8] = {};
        #pragma unroll
        for (int kc = 0; kc < 8; ++kc) {
            const int cur = kc & 1, nxt = cur ^ 1;
            int4 h0, h1, l0, l1;
            if (kc < 7) {
                const ushort* nh = sph + (kc + 1) * 32;
                const ushort* nl = spl + (kc + 1) * 32;
                h0 = *(const int4*)(nh);
                h1 = *(const int4*)(nh + 8);
                l0 = *(const int4*)(nl);
                l1 = *(const int4*)(nl + 8);
            }
            short8v bh[8], bl[8];
            #pragma unroll
            for (int n = 0; n < 8; ++n) {
                int rr = n * 16 + lr;
                bh[n] = *(const short8v*)&Bs[cur][0][rr][hi4 * 8];
                bl[n] = *(const short8v*)&Bs[cur][1][rr][hi4 * 8];
            }
            #pragma unroll
            for (int n = 0; n < 8; ++n) {
                acc[n] = __builtin_amdgcn_mfma_f32_16x16x32_bf16(ah[kc], bh[n], acc[n], 0, 0, 0);
                acc[n] = __builtin_amdgcn_mfma_f32_16x16x32_bf16(ah[kc], bl[n], acc[n], 0, 0, 0);
                acc[n] = __builtin_amdgcn_mfma_f32_16x16x32_bf16(al[kc], bh[n], acc[n], 0, 0, 0);
            }
            if (kc < 7) {
                *(int4*)&Bs[nxt][0][scol][sq * 8]     = h0;
                *(int4*)&Bs[nxt][0][scol][sq * 8 + 8] = h1;
                *(int4*)&Bs[nxt][1][scol][sq * 8]     = l0;
                *(int4*)&Bs[nxt][1][scol][sq * 8 + 8] = l1;
            }
            __syncthreads();
        }

        #pragma unroll
        for (int r = 0; r < 4; ++r) {
            float a0 = tv0[r], a1 = tv1[r], a2 = tv2[r];
            int   b0 = ti0[r], b1 = ti1[r], b2 = ti2[r];
            #pragma unroll
            for (int n = 0; n < 8; ++n) {
                int col = col0 + n * 16 + lr;
                if (col < NPGc)
                    ins3(acc[n][r], col, a0, b0, a1, b1, a2, b2);
            }
            tv0[r] = a0; tv1[r] = a1; tv2[r] = a2;
            ti0[r] = b0; ti1[r] = b1; ti2[r] = b2;
        }
    }

    #pragma unroll
    for (int r = 0; r < 4; ++r) {
        float a0 = tv0[r], a1 = tv1[r], a2 = tv2[r];
        int   b0 = ti0[r], b1 = ti1[r], b2 = ti2[r];
        #pragma unroll
        for (int off = 1; off <= 8; off <<= 1)
            merge3(a0, a1, a2, b0, b1, b2, off);
        if (lr == 0) {
            int row = row0 + w * 16 + hi4 * 4 + r;
            if (row < NPGc) {
                int rg = g * NPGc + row;
                fsrc[rg * 3 + 0] = g * NPGc + b0;
                fsrc[rg * 3 + 1] = g * NPGc + b1;
                fsrc[rg * 3 + 2] = g * NPGc + b2;
            }
        }
    }
}

// ---------------------------------------------------------------------------
// CSR build
// ---------------------------------------------------------------------------
__global__ void hist_kernel(const int* __restrict__ dst, int* __restrict__ cnt, int nE)
{
    int e = blockIdx.x * 256 + threadIdx.x;
    if (e < nE) atomicAdd(&cnt[dst[e]], 1);
}

__global__ void scan1_kernel(const int* __restrict__ in, int* __restrict__ out,
                             int* __restrict__ bsum, int n)
{
    __shared__ int sh[256];
    int t = threadIdx.x;
    int i = blockIdx.x * 256 + t;
    int v = (i < n) ? in[i] : 0;
    sh[t] = v;
    __syncthreads();
    for (int s = 1; s < 256; s <<= 1) {
        int tv = (t >= s) ? sh[t - s] : 0;
        __syncthreads();
        sh[t] += tv;
        __syncthreads();
    }
    if (i < n) out[i] = sh[t] - v;  // exclusive
    if (t == 255) bsum[blockIdx.x] = sh[255];
}

__global__ void scan2_kernel(int* __restrict__ bsum, int nb)
{
    __shared__ int sh[256];
    int t = threadIdx.x;
    int v = (t < nb) ? bsum[t] : 0;
    sh[t] = v;
    __syncthreads();
    for (int s = 1; s < 256; s <<= 1) {
        int tv = (t >= s) ? sh[t - s] : 0;
        __syncthreads();
        sh[t] += tv;
        __syncthreads();
    }
    if (t < nb) bsum[t] = sh[t] - v;
}

__global__ void scan3_kernel(int* __restrict__ out, const int* __restrict__ bsum, int n)
{
    int i = blockIdx.x * 256 + threadIdx.x;
    if (i < n) out[i] += bsum[blockIdx.x];
}

__global__ void fill_kernel(const int* __restrict__ src, const int* __restrict__ dst,
                            const int* __restrict__ row_ptr, int* __restrict__ cursor,
                            int* __restrict__ sorted_src, int nE)
{
    int e = blockIdx.x * 256 + threadIdx.x;
    if (e < nE) {
        int d = dst[e];
        int pos = row_ptr[d] + atomicAdd(&cursor[d], 1);
        sorted_src[pos] = src[e];
    }
}

__global__ void dinv_kernel(const int* __restrict__ cnt, float* __restrict__ dinv, int n)
{
    int i = blockIdx.x * 256 + threadIdx.x;
    if (i < n) dinv[i] = rsqrtf((float)cnt[i] + 1.0f);
}

// ---------------------------------------------------------------------------
// GCN gather (bf16 messages in, bf16 raw out, XCD-bijective swizzle)
// ---------------------------------------------------------------------------
__global__ __launch_bounds__(256)
void gcn_gather(const ushort* __restrict__ m, const int* __restrict__ row_ptr,
                const int* __restrict__ cnt, const int* __restrict__ srcs,
                const float* __restrict__ dinv, const float* __restrict__ bias,
                ushort* __restrict__ out)
{
    int bid = blockIdx.x;
    int xcd = bid & 7, idx = bid >> 3;
    int g = xcd + 8 * (idx / NPGc);
    if (g >= GG) return;
    int n = g * NPGc + (idx % NPGc);
    int c = threadIdx.x;
    float dn = dinv[n];
    float acc = bf2f(m[(size_t)n * HH + c]) * dn;
    int s0 = row_ptr[n], e0 = s0 + cnt[n];
    for (int e = s0; e < e0; ++e) {
        int s = srcs[e];
        acc += bf2f(m[(size_t)s * HH + c]) * dinv[s];
    }
    out[(size_t)n * HH + c] = f2bf(acc * dn + bias[c]);
}

__global__ __launch_bounds__(256)
void fgcn_gather(const ushort* __restrict__ m, const int* __restrict__ fsrc,
                 const float* __restrict__ bias, ushort* __restrict__ out)
{
    int bid = blockIdx.x;
    int xcd = bid & 7, idx = bid >> 3;
    int g = xcd + 8 * (idx / NPGc);
    if (g >= GG) return;
    int n = g * NPGc + (idx % NPGc);
    int c = threadIdx.x;
    int s0 = fsrc[n * 3], s1 = fsrc[n * 3 + 1], s2 = fsrc[n * 3 + 2];
    float acc = bf2f(m[(size_t)n * HH + c]) + bf2f(m[(size_t)s0 * HH + c])
              + bf2f(m[(size_t)s1 * HH + c]) + bf2f(m[(size_t)s2 * HH + c]);
    out[(size_t)n * HH + c] = f2bf(0.25f * acc + bias[c]);
}

// ---------------------------------------------------------------------------
// GraphNorm: chunked partial stats -> tiny reduce (MM = mean*ms, RS = rstd).
// Apply is FUSED into consumer GEMMs (stage + gate epilogue).
// ---------------------------------------------------------------------------
__global__ __launch_bounds__(256)
void norm_stats(const ushort* __restrict__ x, float* __restrict__ S1p, float* __restrict__ S2p)
{
    int g = blockIdx.x, chunk = blockIdx.y, c = threadIdx.x;
    int r0 = chunk * 63, r1 = min(r0 + 63, NPGc);
    float s1 = 0.f, s2 = 0.f;
    for (int r = r0; r < r1; ++r) {
        float v = bf2f(x[((size_t)(g * NPGc + r)) * HH + c]);
        s1 += v; s2 += v * v;
    }
    size_t o = ((size_t)(g * 8 + chunk)) * HH + c;
    S1p[o] = s1;
    S2p[o] = s2;
}

__global__ __launch_bounds__(256)
void norm_reduce(const float* __restrict__ S1p, const float* __restrict__ S2p,
                 const float* __restrict__ ms, float* __restrict__ MM, float* __restrict__ RS)
{
    int g = blockIdx.x, c = threadIdx.x;
    float s1 = 0.f, s2 = 0.f;
    #pragma unroll
    for (int j = 0; j < 8; ++j) {
        size_t po = ((size_t)(g * 8 + j)) * HH + c;
        s1 += S1p[po];
        s2 += S2p[po];
    }
    float mean = s1 / (float)NPGc;
    float mm = mean * ms[c];
    float var = s2 / (float)NPGc - 2.f * mm * mean + mm * mm;
    MM[g * HH + c] = mm;
    RS[g * HH + c] = rsqrtf(var + 1e-5f);
}

// ---------------------------------------------------------------------------
// Pool: gf[g] = (sum H0 + 2*sum H1) / 500   (all_x[-1]==all_x[1] quirk)
// ---------------------------------------------------------------------------
__global__ __launch_bounds__(256)
void pool_kernel(const ushort* __restrict__ X0, const ushort* __restrict__ X1,
                 float* __restrict__ out)
{
    int g = blockIdx.x, c = threadIdx.x;
    float s0 = 0.f, s1 = 0.f;
    for (int r = 0; r < NPGc; ++r) {
        size_t o = ((size_t)(g * NPGc + r)) * HH + c;
        s0 += bf2f(X0[o]);
        s1 += bf2f(X1[o]);
    }
    out[g * HH + c] = (s0 + 2.f * s1) / (float)NPGc;
}

__global__ void sentinel_kernel(float* out, int n)
{
    int i = blockIdx.x * 256 + threadIdx.x;
    if (i < n) out[i] = 12345.0f;
}

// ---------------------------------------------------------------------------
extern "C" void kernel_launch(void* const* d_in, const int* in_sizes, int n_in,
                              void* d_out, int out_size, void* d_ws, size_t ws_size,
                              hipStream_t stream)
{
    const float* x       = (const float*)d_in[0];
    const int* edge_idx  = (const int*)d_in[1];
    const float* emb_W   = (const float*)d_in[3];
    const float* emb_b   = (const float*)d_in[4];
    const float* conv_W  = (const float*)d_in[5];
    const float* conv_b  = (const float*)d_in[6];
    const float* fconv_W = (const float*)d_in[7];
    const float* fconv_b = (const float*)d_in[8];
    const float* norm_w  = (const float*)d_in[9];
    const float* norm_b  = (const float*)d_in[10];
    const float* norm_ms = (const float*)d_in[11];
    const float* fnorm_w = (const float*)d_in[12];
    const float* fnorm_b = (const float*)d_in[13];
    const float* fnorm_ms= (const float*)d_in[14];
    const float* gate_W  = (const float*)d_in[15];
    const float* gate_b  = (const float*)d_in[16];

    const int E = in_sizes[1] / 2;
    const int* esrc = edge_idx;
    const int* edst = edge_idx + E;

    const size_t NHf = (size_t)NN * HH;           // 12.8M elements
    char* p = (char*)d_ws;
    auto alloc = [&](size_t bytes) { char* r = p; p += (bytes + 255) & ~(size_t)255; return r; };
    float*  B0 = (float*)alloc(NHf * 4);          // emb out (f32, feeds knn)
    ushort* Mr = (ushort*)alloc(NHf * 2);         // messages
    ushort* Ar = (ushort*)alloc(NHf * 2);         // h-road raw gather out
    ushort* Br = (ushort*)alloc(NHf * 2);         // f-road raw gather out
    ushort* H0 = (ushort*)alloc(NHf * 2);         // layer0 out
    ushort* H1 = (ushort*)alloc(NHf * 2);         // layer1 out
    ushort* xnh = Mr;                             // knn operands overlay Mr/Ar
    ushort* xnl = Ar;
    int* sorted_src = (int*)alloc((size_t)E * 4);
    int* row_ptr    = (int*)alloc((size_t)NN * 4);
    int* deg_cnt    = (int*)alloc((size_t)NN * 4);
    int* cursor     = (int*)alloc((size_t)NN * 4);
    float* dinv     = (float*)alloc((size_t)NN * 4);
    int* fsrc       = (int*)alloc((size_t)NN * 3 * 4);
    float* S1p      = (float*)alloc((size_t)GG * 8 * HH * 4);
    float* S2p      = (float*)alloc((size_t)GG * 8 * HH * 4);
    float* MMh      = (float*)alloc((size_t)GG * HH * 4);
    float* RSh      = (float*)alloc((size_t)GG * HH * 4);
    float* MMf      = (float*)alloc((size_t)GG * HH * 4);
    float* RSf      = (float*)alloc((size_t)GG * HH * 4);
    int* bsum       = (int*)alloc(1024);
    ushort* wts     = (ushort*)alloc((size_t)425984 * 2);  // all W^T bf16
    size_t needed = (size_t)(p - (char*)d_ws);
    if (ws_size < needed) {
        sentinel_kernel<<<(out_size + 255) / 256, 256, 0, stream>>>((float*)d_out, out_size);
        return;
    }
    ushort* embWt   = wts;                    // [256][128]
    ushort* convWt0 = wts + 32768;            // [256][256]
    ushort* convWt1 = wts + 98304;
    ushort* fconvWt0 = wts + 163840;
    ushort* fconvWt1 = wts + 229376;
    ushort* gateWt  = wts + 294912;           // [256][512]

    const int nScanB = (NN + 255) / 256;  // 196
    const int gatherGrid = 8 * 13 * NPGc; // 52000 (XCD-bijective, skip g>=100)
    const int gemmGrid = 8 * 49 * 2;      // 784 (XCD-paired rowblk/colblk)

    hipMemsetAsync(deg_cnt, 0, (size_t)NN * 4, stream);
    hipMemsetAsync(cursor, 0, (size_t)NN * 4, stream);

    // 0. all weight transposes+cvt in one launch
    wcvt_all<<<1664, 256, 0, stream>>>(emb_W, conv_W, fconv_W, gate_W, wts);

    // 1. embedding: h0 = x @ emb_W + emb_b -> B0 (f32)
    gemm_mfma<<<gemmGrid, 256, 0, stream>>>(x, nullptr, 0, embWt, emb_b, B0, nullptr,
                                            NN, IND, IND, 0, nullptr, 0,
                                            nullptr, nullptr, nullptr, nullptr,
                                            nullptr, nullptr, nullptr, nullptr);

    // 2. CSR of edge_index by dst
    hist_kernel<<<(E + 255) / 256, 256, 0, stream>>>(edst, deg_cnt, E);
    scan1_kernel<<<nScanB, 256, 0, stream>>>(deg_cnt, row_ptr, bsum, NN);
    scan2_kernel<<<1, 256, 0, stream>>>(bsum, nScanB);
    scan3_kernel<<<nScanB, 256, 0, stream>>>(row_ptr, bsum, NN);
    fill_kernel<<<(E + 255) / 256, 256, 0, stream>>>(esrc, edst, row_ptr, cursor, sorted_src, E);
    dinv_kernel<<<(NN + 255) / 256, 256, 0, stream>>>(deg_cnt, dinv, NN);

    // 3. knn graph from h0 (hi/lo split, fused sim+topk)
    row_norm_hl<<<NN, 256, 0, stream>>>(B0, xnh, xnl);
    simtopk<<<832, 256, 0, stream>>>(xnh, xnl, fsrc);

    // 4. layers (bf16 raw activations; norm fused into consumers)
    dim3 ngrid(GG, 8);
    const void* hptr = (const void*)B0;   // prev/conv-input; f32 for layer 0
    int habf = 0;
    ushort* Hout[2] = { H0, H1 };
    for (int i = 0; i < 2; ++i) {
        const ushort* Wc = (i == 0) ? convWt0 : convWt1;
        const ushort* Wf = (i == 0) ? fconvWt0 : fconvWt1;
        const float* bc  = conv_b  + (size_t)i * HH;
        const float* bfb = fconv_b + (size_t)i * HH;
        const float* nw  = norm_w  + (size_t)i * HH;
        const float* nb  = norm_b  + (size_t)i * HH;
        const float* nms = norm_ms + (size_t)i * HH;
        const float* fw  = fnorm_w + (size_t)i * HH;
        const float* fb  = fnorm_b + (size_t)i * HH;
        const float* fms = fnorm_ms+ (size_t)i * HH;
        // h-road conv -> bf16 messages (A raw, no norm)
        gemm_mfma<<<gemmGrid, 256, 0, stream>>>(hptr, nullptr, habf, Wc, nullptr, nullptr, Mr,
                                                NN, HH, HH, 2, nullptr, 0,
                                                nullptr, nullptr, nullptr, nullptr,
                                                nullptr, nullptr, nullptr, nullptr);
        gcn_gather<<<gatherGrid, 256, 0, stream>>>(Mr, row_ptr, deg_cnt, sorted_src,
                                                   dinv, bc, Ar);
        norm_stats<<<ngrid, 256, 0, stream>>>(Ar, S1p, S2p);
        norm_reduce<<<GG, 256, 0, stream>>>(S1p, S2p, nms, MMh, RSh);
        // f-road conv (A = normed(Ar) on the fly) -> bf16 messages
        gemm_mfma<<<gemmGrid, 256, 0, stream>>>(Ar, nullptr, 1, Wf, nullptr, nullptr, Mr,
                                                NN, HH, HH, 2, nullptr, 0,
                                                MMh, RSh, nw, nb,
                                                nullptr, nullptr, nullptr, nullptr);
        fgcn_gather<<<gatherGrid, 256, 0, stream>>>(Mr, fsrc, bfb, Br);
        norm_stats<<<ngrid, 256, 0, stream>>>(Br, S1p, S2p);
        norm_reduce<<<GG, 256, 0, stream>>>(S1p, S2p, fms, MMf, RSf);
        // gate + combine: A/A2 normed on stage AND in epilogue -> bf16 H_i
        gemm_mfma<<<gemmGrid, 256, 0, stream>>>(Ar, Br, 1, gateWt, gate_b, nullptr, Hout[i],
                                                NN, 2 * HH, HH, 1, hptr, habf,
                                                MMh, RSh, nw, nb,
                                                MMf, RSf, fw, fb);
        hptr = (const void*)Hout[i];
        habf = 1;
    }
    // all_x[0]=H0, all_x[1]=H1: gf = (sum H0 + 2*sum H1)/500
    pool_kernel<<<GG, 256, 0, stream>>>(H0, H1, (float*)d_out);
}

// Round 15
// 1220.218 us; speedup vs baseline: 1.2155x; 1.0239x over previous
//
#include <hip/hip_runtime.h>
#include <math.h>

#define NN 50000      // nodes
#define GG 100        // graphs
#define NPGc 500      // nodes per graph
#define HH 256        // hidden
#define IND 128       // input dim

typedef __attribute__((ext_vector_type(8))) short short8v;  // 8 bf16
typedef __attribute__((ext_vector_type(4))) float f32x4;

__device__ __forceinline__ ushort f2bf(float f) {
    union { float f; unsigned u; } v; v.f = f;
    unsigned r = (v.u + 0x7fffu + ((v.u >> 16) & 1u)) >> 16;  // RNE
    return (ushort)r;
}
__device__ __forceinline__ float bf2f(ushort h) {
    union { unsigned u; float f; } v; v.u = ((unsigned)h) << 16;
    return v.f;
}
__device__ __forceinline__ float lrelu(float v) { return v > 0.f ? v : 0.01f * v; }

// LDS ushort-index swizzle: XOR 16B-granule bits with row&7 (T2)
__device__ __forceinline__ int swz(int row, int kidx) { return kidx ^ ((row & 7) << 3); }

// ---------------------------------------------------------------------------
// All weight transposes+converts in ONE launch. dst layout (ushort elems):
// [0,32768) embWt [256][128] | [32768,98304) convWt0 | [98304,163840) convWt1
// [163840,229376) fconvWt0 | [229376,294912) fconvWt1 | [294912,425984) gateWt
// ---------------------------------------------------------------------------
__global__ void wcvt_all(const float* __restrict__ emb_W, const float* __restrict__ conv_W,
                         const float* __restrict__ fconv_W, const float* __restrict__ gate_W,
                         ushort* __restrict__ dst)
{
    int i = blockIdx.x * 256 + threadIdx.x;
    if (i >= 425984) return;
    float v;
    if (i < 32768)       { int n = i >> 7, k = i & 127;              v = emb_W[(size_t)k * 256 + n]; }
    else if (i < 98304)  { int j = i - 32768;  int n = j >> 8, k = j & 255; v = conv_W[(size_t)k * 256 + n]; }
    else if (i < 163840) { int j = i - 98304;  int n = j >> 8, k = j & 255; v = conv_W[65536 + (size_t)k * 256 + n]; }
    else if (i < 229376) { int j = i - 163840; int n = j >> 8, k = j & 255; v = fconv_W[(size_t)k * 256 + n]; }
    else if (i < 294912) { int j = i - 229376; int n = j >> 8, k = j & 255; v = fconv_W[65536 + (size_t)k * 256 + n]; }
    else                 { int j = i - 294912; int n = j >> 9, k = j & 511; v = gate_W[(size_t)k * 256 + n]; }
    dst[i] = f2bf(v);
}

// ---------------------------------------------------------------------------
// bf16 MFMA GEMM with FUSED GraphNorm-apply on operands (as round 14).
// ---------------------------------------------------------------------------
__global__ __launch_bounds__(256)
void gemm_mfma(const void* __restrict__ Av, const void* __restrict__ A2v, int abf,
               const ushort* __restrict__ Wt, const float* __restrict__ bias,
               float* __restrict__ C, ushort* __restrict__ Cbf,
               int M, int K, int lda, int mode,
               const void* __restrict__ prevv, int prevbf,
               const float* __restrict__ MMa, const float* __restrict__ RSa,
               const float* __restrict__ nwa, const float* __restrict__ nba,
               const float* __restrict__ MMb, const float* __restrict__ RSb,
               const float* __restrict__ nwb, const float* __restrict__ nbb)
{
    __shared__ ushort As[128][64];
    __shared__ ushort Bs[128][64];
    const int bid = blockIdx.x;
    const int xcd = bid & 7;
    const int t = bid >> 3;
    const int cb = t & 1;
    const int rowblk = (t >> 1) * 8 + xcd;
    const int row0 = rowblk * 128;
    if (row0 >= M) return;
    const int col0 = cb * 128;
    const int tid = threadIdx.x;
    const int lane = tid & 63;
    const int w = tid >> 6;
    const int wr = (w >> 1) * 64, wc = (w & 1) * 64;
    const int lr = lane & 15, lk = (lane >> 4) * 8;
    f32x4 acc[4][4] = {};

    for (int k0 = 0; k0 < K; k0 += 64) {
        __syncthreads();
        #pragma unroll
        for (int it = 0; it < 4; ++it) {           // stage A: 128x64
            int c = it * 256 + tid;
            int row = c >> 3, col = (c & 7) * 8;
            int gr = row0 + row; if (gr > M - 1) gr = M - 1;
            int kk = k0 + col;
            if (abf) {
                const ushort* Ap = (const ushort*)Av;
                const float *MMp = MMa, *RSp = RSa, *wp = nwa, *bp = nba;
                if (A2v != nullptr && kk >= 256) {
                    Ap = (const ushort*)A2v; kk -= 256;
                    MMp = MMb; RSp = RSb; wp = nwb; bp = nbb;
                }
                int4 raw = *(const int4*)&Ap[(size_t)gr * lda + kk];
                if (MMp != nullptr) {
                    int g = gr / NPGc;
                    const ushort* rp = (const ushort*)&raw;
                    float4 mm0 = *(const float4*)&MMp[(size_t)g * HH + kk];
                    float4 mm1 = *(const float4*)&MMp[(size_t)g * HH + kk + 4];
                    float4 rs0 = *(const float4*)&RSp[(size_t)g * HH + kk];
                    float4 rs1 = *(const float4*)&RSp[(size_t)g * HH + kk + 4];
                    float4 w0 = *(const float4*)&wp[kk];
                    float4 w1 = *(const float4*)&wp[kk + 4];
                    float4 b0 = *(const float4*)&bp[kk];
                    float4 b1 = *(const float4*)&bp[kk + 4];
                    float mms[8] = { mm0.x, mm0.y, mm0.z, mm0.w, mm1.x, mm1.y, mm1.z, mm1.w };
                    float rss[8] = { rs0.x, rs0.y, rs0.z, rs0.w, rs1.x, rs1.y, rs1.z, rs1.w };
                    float wss[8] = { w0.x, w0.y, w0.z, w0.w, w1.x, w1.y, w1.z, w1.w };
                    float bss[8] = { b0.x, b0.y, b0.z, b0.w, b1.x, b1.y, b1.z, b1.w };
                    union { ushort u[8]; int4 q; } pk;
                    #pragma unroll
                    for (int j = 0; j < 8; ++j) {
                        float v = bf2f(rp[j]);
                        pk.u[j] = f2bf(lrelu(wss[j] * (v - mms[j]) * rss[j] + bss[j]));
                    }
                    *(int4*)&As[row][swz(row, col)] = pk.q;
                } else {
                    *(int4*)&As[row][swz(row, col)] = raw;
                }
            } else {
                const float* Ap = (const float*)Av;
                if (A2v != nullptr && kk >= 256) { Ap = (const float*)A2v; kk -= 256; }
                const float* s = &Ap[(size_t)gr * lda + kk];
                float4 v0 = *(const float4*)s;
                float4 v1 = *(const float4*)(s + 4);
                union { ushort u[8]; int4 q; } pk;
                pk.u[0] = f2bf(v0.x); pk.u[1] = f2bf(v0.y); pk.u[2] = f2bf(v0.z); pk.u[3] = f2bf(v0.w);
                pk.u[4] = f2bf(v1.x); pk.u[5] = f2bf(v1.y); pk.u[6] = f2bf(v1.z); pk.u[7] = f2bf(v1.w);
                *(int4*)&As[row][swz(row, col)] = pk.q;
            }
        }
        #pragma unroll
        for (int it = 0; it < 4; ++it) {           // stage B: Wt rows col0..+127
            int c = it * 256 + tid;
            int n = c >> 3, k = (c & 7) * 8;
            *(int4*)&Bs[n][swz(n, k)] = *(const int4*)&Wt[(size_t)(col0 + n) * K + k0 + k];
        }
        __syncthreads();
        #pragma unroll
        for (int ks = 0; ks < 2; ++ks) {
            short8v av[4], bv[4];
            #pragma unroll
            for (int m = 0; m < 4; ++m) {
                int rr = wr + m * 16 + lr;
                av[m] = *(const short8v*)&As[rr][swz(rr, ks * 32 + lk)];
            }
            #pragma unroll
            for (int n = 0; n < 4; ++n) {
                int rr = wc + n * 16 + lr;
                bv[n] = *(const short8v*)&Bs[rr][swz(rr, ks * 32 + lk)];
            }
            #pragma unroll
            for (int m = 0; m < 4; ++m)
                #pragma unroll
                for (int n = 0; n < 4; ++n)
                    acc[m][n] = __builtin_amdgcn_mfma_f32_16x16x32_bf16(av[m], bv[n], acc[m][n], 0, 0, 0);
        }
    }
    const int fr = (lane >> 4) * 4;
    if (mode == 0) {
        #pragma unroll
        for (int n = 0; n < 4; ++n) {
            int col = col0 + wc + n * 16 + lr;
            float bb = bias ? bias[col] : 0.f;
            #pragma unroll
            for (int m = 0; m < 4; ++m) {
                int rbase = row0 + wr + m * 16 + fr;
                #pragma unroll
                for (int r = 0; r < 4; ++r) {
                    int row = rbase + r;
                    if (row < M) C[(size_t)row * HH + col] = acc[m][n][r] + bb;
                }
            }
        }
    } else if (mode == 2) {
        #pragma unroll
        for (int n = 0; n < 4; ++n) {
            int col = col0 + wc + n * 16 + lr;
            float bb = bias ? bias[col] : 0.f;
            #pragma unroll
            for (int m = 0; m < 4; ++m) {
                int rbase = row0 + wr + m * 16 + fr;
                #pragma unroll
                for (int r = 0; r < 4; ++r) {
                    int row = rbase + r;
                    if (row < M) Cbf[(size_t)row * HH + col] = f2bf(acc[m][n][r] + bb);
                }
            }
        }
    } else {
        const ushort* hraw = (const ushort*)Av;
        const ushort* fraw = (const ushort*)A2v;
        #pragma unroll
        for (int n = 0; n < 4; ++n) {
            int col = col0 + wc + n * 16 + lr;
            float gb = bias[col];
            float wh = nwa[col], bh = nba[col];
            float wf = nwb[col], bf2 = nbb[col];
            #pragma unroll
            for (int m = 0; m < 4; ++m) {
                int rbase = row0 + wr + m * 16 + fr;
                #pragma unroll
                for (int r = 0; r < 4; ++r) {
                    int row = rbase + r;
                    if (row < M) {
                        size_t o = (size_t)row * HH + col;
                        int g = row / NPGc;
                        size_t go = (size_t)g * HH + col;
                        float z = acc[m][n][r] + gb;
                        float s = 1.f / (1.f + expf(-z));
                        float hv = lrelu(wh * (bf2f(hraw[o]) - MMa[go]) * RSa[go] + bh);
                        float fv = lrelu(wf * (bf2f(fraw[o]) - MMb[go]) * RSb[go] + bf2);
                        float pv = prevbf ? bf2f(((const ushort*)prevv)[o])
                                          : ((const float*)prevv)[o];
                        Cbf[o] = f2bf(s * hv + (1.f - s) * fv + pv);
                    }
                }
            }
        }
    }
}

// ---------------------------------------------------------------------------
// Row L2-normalize (f32 in), emit bf16 (hi only)
// ---------------------------------------------------------------------------
__global__ __launch_bounds__(256)
void row_norm_h(const float* __restrict__ h, ushort* __restrict__ xh)
{
    int n = blockIdx.x, c = threadIdx.x;
    float v = h[(size_t)n * HH + c];
    __shared__ float red[256];
    red[c] = v * v;
    __syncthreads();
    for (int s = 128; s > 0; s >>= 1) {
        if (c < s) red[c] += red[c + s];
        __syncthreads();
    }
    float norm = sqrtf(red[0]);
    xh[(size_t)n * HH + c] = f2bf(v / (norm + 1e-12f));
}

// ---------------------------------------------------------------------------
// top-3 helpers (exact top_k tie-breaking: value desc, index asc)
// ---------------------------------------------------------------------------
__device__ __forceinline__ bool tk_better(float va, int ia, float vb, int ib)
{
    return (va > vb) || (va == vb && ia < ib);
}

__device__ __forceinline__ void ins3(float v, int i,
                                     float& a0, int& b0, float& a1, int& b1,
                                     float& a2, int& b2)
{
    if (tk_better(v, i, a0, b0))      { a2 = a1; b2 = b1; a1 = a0; b1 = b0; a0 = v; b0 = i; }
    else if (tk_better(v, i, a1, b1)) { a2 = a1; b2 = b1; a1 = v;  b1 = i; }
    else if (tk_better(v, i, a2, b2)) { a2 = v;  b2 = i; }
}

__device__ __forceinline__ void merge3(float& v0, float& v1, float& v2,
                                       int& i0, int& i1, int& i2, int off)
{
    float w0 = __shfl_xor(v0, off), w1 = __shfl_xor(v1, off), w2 = __shfl_xor(v2, off);
    int   j0 = __shfl_xor(i0, off), j1 = __shfl_xor(i1, off), j2 = __shfl_xor(i2, off);
    float avv[3] = { v0, v1, v2 }, bvv[3] = { w0, w1, w2 };
    int   aii[3] = { i0, i1, i2 }, bii[3] = { j0, j1, j2 };
    float rv[3]; int ri[3];
    int p = 0, q = 0;
    #pragma unroll
    for (int t = 0; t < 3; ++t) {
        bool takeA = tk_better(avv[p], aii[p], bvv[q], bii[q]);
        rv[t] = takeA ? avv[p] : bvv[q];
        ri[t] = takeA ? aii[p] : bii[q];
        if (takeA) ++p; else ++q;
    }
    v0 = rv[0]; v1 = rv[1]; v2 = rv[2];
    i0 = ri[0]; i1 = ri[1]; i2 = ri[2];
}

// ---------------------------------------------------------------------------
// simtopk hi-only: reg-A + dbuf-B fused sim + top-3. 1x MFMA (was 3x with
// hi/lo), half staging traffic, LDS 18KB, A-frags 32 VGPR.
// Block = 64 rows of one graph; wave = 16 rows x 128 cols. XCD-swizzled.
// ---------------------------------------------------------------------------
__global__ __launch_bounds__(256)
void simtopk(const ushort* __restrict__ xnh, int* __restrict__ fsrc)
{
    __shared__ ushort Bs[2][128][36];   // [buf][col][k(32)+pad4] = 18 KB
    const int bid = blockIdx.x;
    const int xcd = bid & 7;
    const int rb  = (bid >> 3) & 7;
    const int g   = (bid >> 6) * 8 + xcd;
    if (g >= GG) return;
    const int row0 = rb * 64;
    const int tid  = threadIdx.x;
    const int lane = tid & 63;
    const int w    = tid >> 6;
    const int lr   = lane & 15;
    const int hi4  = lane >> 4;
    const size_t base = (size_t)g * NPGc * HH;

    // ---- A fragments in registers: full K, wave's 16 rows ----
    int arow = row0 + w * 16 + lr; if (arow > NPGc - 1) arow = NPGc - 1;
    const ushort* aph = xnh + base + (size_t)arow * HH + hi4 * 8;
    short8v ah[8];
    #pragma unroll
    for (int kc = 0; kc < 8; ++kc)
        ah[kc] = *(const short8v*)(aph + kc * 32);

    const int scol = tid >> 1;             // 0..127
    const int sq   = (tid & 1) * 2;        // granule 0 or 2

    float tv0[4], tv1[4], tv2[4];
    int   ti0[4], ti1[4], ti2[4];
    #pragma unroll
    for (int r = 0; r < 4; ++r) {
        tv0[r] = tv1[r] = tv2[r] = -2.f;
        ti0[r] = ti1[r] = ti2[r] = 0x7fffffff;
    }

    for (int ct = 0; ct < 4; ++ct) {
        const int col0 = ct * 128;
        int gcol = col0 + scol; if (gcol > NPGc - 1) gcol = NPGc - 1;
        const ushort* sph = xnh + base + (size_t)gcol * HH + sq * 8;

        {   // prologue: stage chunk 0 into buf 0
            int4 h0 = *(const int4*)(sph);
            int4 h1 = *(const int4*)(sph + 8);
            *(int4*)&Bs[0][scol][sq * 8]     = h0;
            *(int4*)&Bs[0][scol][sq * 8 + 8] = h1;
        }
        __syncthreads();

        f32x4 acc[8] = {};
        #pragma unroll
        for (int kc = 0; kc < 8; ++kc) {
            const int cur = kc & 1, nxt = cur ^ 1;
            int4 h0, h1;
            if (kc < 7) {
                const ushort* nh = sph + (kc + 1) * 32;
                h0 = *(const int4*)(nh);
                h1 = *(const int4*)(nh + 8);
            }
            short8v bh[8];
            #pragma unroll
            for (int n = 0; n < 8; ++n)
                bh[n] = *(const short8v*)&Bs[cur][n * 16 + lr][hi4 * 8];
            #pragma unroll
            for (int n = 0; n < 8; ++n)
                acc[n] = __builtin_amdgcn_mfma_f32_16x16x32_bf16(ah[kc], bh[n], acc[n], 0, 0, 0);
            if (kc < 7) {
                *(int4*)&Bs[nxt][scol][sq * 8]     = h0;
                *(int4*)&Bs[nxt][scol][sq * 8 + 8] = h1;
            }
            __syncthreads();
        }

        #pragma unroll
        for (int r = 0; r < 4; ++r) {
            float a0 = tv0[r], a1 = tv1[r], a2 = tv2[r];
            int   b0 = ti0[r], b1 = ti1[r], b2 = ti2[r];
            #pragma unroll
            for (int n = 0; n < 8; ++n) {
                int col = col0 + n * 16 + lr;
                if (col < NPGc)
                    ins3(acc[n][r], col, a0, b0, a1, b1, a2, b2);
            }
            tv0[r] = a0; tv1[r] = a1; tv2[r] = a2;
            ti0[r] = b0; ti1[r] = b1; ti2[r] = b2;
        }
    }

    #pragma unroll
    for (int r = 0; r < 4; ++r) {
        float a0 = tv0[r], a1 = tv1[r], a2 = tv2[r];
        int   b0 = ti0[r], b1 = ti1[r], b2 = ti2[r];
        #pragma unroll
        for (int off = 1; off <= 8; off <<= 1)
            merge3(a0, a1, a2, b0, b1, b2, off);
        if (lr == 0) {
            int row = row0 + w * 16 + hi4 * 4 + r;
            if (row < NPGc) {
                int rg = g * NPGc + row;
                fsrc[rg * 3 + 0] = g * NPGc + b0;
                fsrc[rg * 3 + 1] = g * NPGc + b1;
                fsrc[rg * 3 + 2] = g * NPGc + b2;
            }
        }
    }
}

// ---------------------------------------------------------------------------
// CSR build
// ---------------------------------------------------------------------------
__global__ void hist_kernel(const int* __restrict__ dst, int* __restrict__ cnt, int nE)
{
    int e = blockIdx.x * 256 + threadIdx.x;
    if (e < nE) atomicAdd(&cnt[dst[e]], 1);
}

__global__ void scan1_kernel(const int* __restrict__ in, int* __restrict__ out,
                             int* __restrict__ bsum, int n)
{
    __shared__ int sh[256];
    int t = threadIdx.x;
    int i = blockIdx.x * 256 + t;
    int v = (i < n) ? in[i] : 0;
    sh[t] = v;
    __syncthreads();
    for (int s = 1; s < 256; s <<= 1) {
        int tv = (t >= s) ? sh[t - s] : 0;
        __syncthreads();
        sh[t] += tv;
        __syncthreads();
    }
    if (i < n) out[i] = sh[t] - v;  // exclusive
    if (t == 255) bsum[blockIdx.x] = sh[255];
}

__global__ void scan2_kernel(int* __restrict__ bsum, int nb)
{
    __shared__ int sh[256];
    int t = threadIdx.x;
    int v = (t < nb) ? bsum[t] : 0;
    sh[t] = v;
    __syncthreads();
    for (int s = 1; s < 256; s <<= 1) {
        int tv = (t >= s) ? sh[t - s] : 0;
        __syncthreads();
        sh[t] += tv;
        __syncthreads();
    }
    if (t < nb) bsum[t] = sh[t] - v;
}

__global__ void scan3_kernel(int* __restrict__ out, const int* __restrict__ bsum, int n)
{
    int i = blockIdx.x * 256 + threadIdx.x;
    if (i < n) out[i] += bsum[blockIdx.x];
}

__global__ void fill_kernel(const int* __restrict__ src, const int* __restrict__ dst,
                            const int* __restrict__ row_ptr, int* __restrict__ cursor,
                            int* __restrict__ sorted_src, int nE)
{
    int e = blockIdx.x * 256 + threadIdx.x;
    if (e < nE) {
        int d = dst[e];
        int pos = row_ptr[d] + atomicAdd(&cursor[d], 1);
        sorted_src[pos] = src[e];
    }
}

__global__ void dinv_kernel(const int* __restrict__ cnt, float* __restrict__ dinv, int n)
{
    int i = blockIdx.x * 256 + threadIdx.x;
    if (i < n) dinv[i] = rsqrtf((float)cnt[i] + 1.0f);
}

// ---------------------------------------------------------------------------
// GCN gather (bf16 messages in, bf16 raw out, XCD-bijective swizzle)
// ---------------------------------------------------------------------------
__global__ __launch_bounds__(256)
void gcn_gather(const ushort* __restrict__ m, const int* __restrict__ row_ptr,
                const int* __restrict__ cnt, const int* __restrict__ srcs,
                const float* __restrict__ dinv, const float* __restrict__ bias,
                ushort* __restrict__ out)
{
    int bid = blockIdx.x;
    int xcd = bid & 7, idx = bid >> 3;
    int g = xcd + 8 * (idx / NPGc);
    if (g >= GG) return;
    int n = g * NPGc + (idx % NPGc);
    int c = threadIdx.x;
    float dn = dinv[n];
    float acc = bf2f(m[(size_t)n * HH + c]) * dn;
    int s0 = row_ptr[n], e0 = s0 + cnt[n];
    for (int e = s0; e < e0; ++e) {
        int s = srcs[e];
        acc += bf2f(m[(size_t)s * HH + c]) * dinv[s];
    }
    out[(size_t)n * HH + c] = f2bf(acc * dn + bias[c]);
}

__global__ __launch_bounds__(256)
void fgcn_gather(const ushort* __restrict__ m, const int* __restrict__ fsrc,
                 const float* __restrict__ bias, ushort* __restrict__ out)
{
    int bid = blockIdx.x;
    int xcd = bid & 7, idx = bid >> 3;
    int g = xcd + 8 * (idx / NPGc);
    if (g >= GG) return;
    int n = g * NPGc + (idx % NPGc);
    int c = threadIdx.x;
    int s0 = fsrc[n * 3], s1 = fsrc[n * 3 + 1], s2 = fsrc[n * 3 + 2];
    float acc = bf2f(m[(size_t)n * HH + c]) + bf2f(m[(size_t)s0 * HH + c])
              + bf2f(m[(size_t)s1 * HH + c]) + bf2f(m[(size_t)s2 * HH + c]);
    out[(size_t)n * HH + c] = f2bf(0.25f * acc + bias[c]);
}

// ---------------------------------------------------------------------------
// GraphNorm: chunked partial stats -> tiny reduce (MM = mean*ms, RS = rstd).
// Apply is FUSED into consumer GEMMs (stage + gate epilogue).
// ---------------------------------------------------------------------------
__global__ __launch_bounds__(256)
void norm_stats(const ushort* __restrict__ x, float* __restrict__ S1p, float* __restrict__ S2p)
{
    int g = blockIdx.x, chunk = blockIdx.y, c = threadIdx.x;
    int r0 = chunk * 63, r1 = min(r0 + 63, NPGc);
    float s1 = 0.f, s2 = 0.f;
    for (int r = r0; r < r1; ++r) {
        float v = bf2f(x[((size_t)(g * NPGc + r)) * HH + c]);
        s1 += v; s2 += v * v;
    }
    size_t o = ((size_t)(g * 8 + chunk)) * HH + c;
    S1p[o] = s1;
    S2p[o] = s2;
}

__global__ __launch_bounds__(256)
void norm_reduce(const float* __restrict__ S1p, const float* __restrict__ S2p,
                 const float* __restrict__ ms, float* __restrict__ MM, float* __restrict__ RS)
{
    int g = blockIdx.x, c = threadIdx.x;
    float s1 = 0.f, s2 = 0.f;
    #pragma unroll
    for (int j = 0; j < 8; ++j) {
        size_t po = ((size_t)(g * 8 + j)) * HH + c;
        s1 += S1p[po];
        s2 += S2p[po];
    }
    float mean = s1 / (float)NPGc;
    float mm = mean * ms[c];
    float var = s2 / (float)NPGc - 2.f * mm * mean + mm * mm;
    MM[g * HH + c] = mm;
    RS[g * HH + c] = rsqrtf(var + 1e-5f);
}

// ---------------------------------------------------------------------------
// Pool: gf[g] = (sum H0 + 2*sum H1) / 500   (all_x[-1]==all_x[1] quirk)
// ---------------------------------------------------------------------------
__global__ __launch_bounds__(256)
void pool_kernel(const ushort* __restrict__ X0, const ushort* __restrict__ X1,
                 float* __restrict__ out)
{
    int g = blockIdx.x, c = threadIdx.x;
    float s0 = 0.f, s1 = 0.f;
    for (int r = 0; r < NPGc; ++r) {
        size_t o = ((size_t)(g * NPGc + r)) * HH + c;
        s0 += bf2f(X0[o]);
        s1 += bf2f(X1[o]);
    }
    out[g * HH + c] = (s0 + 2.f * s1) / (float)NPGc;
}

__global__ void sentinel_kernel(float* out, int n)
{
    int i = blockIdx.x * 256 + threadIdx.x;
    if (i < n) out[i] = 12345.0f;
}

// ---------------------------------------------------------------------------
extern "C" void kernel_launch(void* const* d_in, const int* in_sizes, int n_in,
                              void* d_out, int out_size, void* d_ws, size_t ws_size,
                              hipStream_t stream)
{
    const float* x       = (const float*)d_in[0];
    const int* edge_idx  = (const int*)d_in[1];
    const float* emb_W   = (const float*)d_in[3];
    const float* emb_b   = (const float*)d_in[4];
    const float* conv_W  = (const float*)d_in[5];
    const float* conv_b  = (const float*)d_in[6];
    const float* fconv_W = (const float*)d_in[7];
    const float* fconv_b = (const float*)d_in[8];
    const float* norm_w  = (const float*)d_in[9];
    const float* norm_b  = (const float*)d_in[10];
    const float* norm_ms = (const float*)d_in[11];
    const float* fnorm_w = (const float*)d_in[12];
    const float* fnorm_b = (const float*)d_in[13];
    const float* fnorm_ms= (const float*)d_in[14];
    const float* gate_W  = (const float*)d_in[15];
    const float* gate_b  = (const float*)d_in[16];

    const int E = in_sizes[1] / 2;
    const int* esrc = edge_idx;
    const int* edst = edge_idx + E;

    const size_t NHf = (size_t)NN * HH;           // 12.8M elements
    char* p = (char*)d_ws;
    auto alloc = [&](size_t bytes) { char* r = p; p += (bytes + 255) & ~(size_t)255; return r; };
    float*  B0 = (float*)alloc(NHf * 4);          // emb out (f32, feeds knn)
    ushort* Mr = (ushort*)alloc(NHf * 2);         // messages
    ushort* Ar = (ushort*)alloc(NHf * 2);         // h-road raw gather out
    ushort* Br = (ushort*)alloc(NHf * 2);         // f-road raw gather out
    ushort* H0 = (ushort*)alloc(NHf * 2);         // layer0 out
    ushort* H1 = (ushort*)alloc(NHf * 2);         // layer1 out
    ushort* xnh = Mr;                             // knn operand overlays Mr
    int* sorted_src = (int*)alloc((size_t)E * 4);
    int* row_ptr    = (int*)alloc((size_t)NN * 4);
    int* deg_cnt    = (int*)alloc((size_t)NN * 4);
    int* cursor     = (int*)alloc((size_t)NN * 4);
    float* dinv     = (float*)alloc((size_t)NN * 4);
    int* fsrc       = (int*)alloc((size_t)NN * 3 * 4);
    float* S1p      = (float*)alloc((size_t)GG * 8 * HH * 4);
    float* S2p      = (float*)alloc((size_t)GG * 8 * HH * 4);
    float* MMh      = (float*)alloc((size_t)GG * HH * 4);
    float* RSh      = (float*)alloc((size_t)GG * HH * 4);
    float* MMf      = (float*)alloc((size_t)GG * HH * 4);
    float* RSf      = (float*)alloc((size_t)GG * HH * 4);
    int* bsum       = (int*)alloc(1024);
    ushort* wts     = (ushort*)alloc((size_t)425984 * 2);  // all W^T bf16
    size_t needed = (size_t)(p - (char*)d_ws);
    if (ws_size < needed) {
        sentinel_kernel<<<(out_size + 255) / 256, 256, 0, stream>>>((float*)d_out, out_size);
        return;
    }
    ushort* embWt   = wts;                    // [256][128]
    ushort* convWt0 = wts + 32768;            // [256][256]
    ushort* convWt1 = wts + 98304;
    ushort* fconvWt0 = wts + 163840;
    ushort* fconvWt1 = wts + 229376;
    ushort* gateWt  = wts + 294912;           // [256][512]

    const int nScanB = (NN + 255) / 256;  // 196
    const int gatherGrid = 8 * 13 * NPGc; // 52000 (XCD-bijective, skip g>=100)
    const int gemmGrid = 8 * 49 * 2;      // 784 (XCD-paired rowblk/colblk)

    hipMemsetAsync(deg_cnt, 0, (size_t)NN * 4, stream);
    hipMemsetAsync(cursor, 0, (size_t)NN * 4, stream);

    // 0. all weight transposes+cvt in one launch
    wcvt_all<<<1664, 256, 0, stream>>>(emb_W, conv_W, fconv_W, gate_W, wts);

    // 1. embedding: h0 = x @ emb_W + emb_b -> B0 (f32)
    gemm_mfma<<<gemmGrid, 256, 0, stream>>>(x, nullptr, 0, embWt, emb_b, B0, nullptr,
                                            NN, IND, IND, 0, nullptr, 0,
                                            nullptr, nullptr, nullptr, nullptr,
                                            nullptr, nullptr, nullptr, nullptr);

    // 2. CSR of edge_index by dst
    hist_kernel<<<(E + 255) / 256, 256, 0, stream>>>(edst, deg_cnt, E);
    scan1_kernel<<<nScanB, 256, 0, stream>>>(deg_cnt, row_ptr, bsum, NN);
    scan2_kernel<<<1, 256, 0, stream>>>(bsum, nScanB);
    scan3_kernel<<<nScanB, 256, 0, stream>>>(row_ptr, bsum, NN);
    fill_kernel<<<(E + 255) / 256, 256, 0, stream>>>(esrc, edst, row_ptr, cursor, sorted_src, E);
    dinv_kernel<<<(NN + 255) / 256, 256, 0, stream>>>(deg_cnt, dinv, NN);

    // 3. knn graph from h0 (hi-only bf16, fused sim+topk)
    row_norm_h<<<NN, 256, 0, stream>>>(B0, xnh);
    simtopk<<<832, 256, 0, stream>>>(xnh, fsrc);

    // 4. layers (bf16 raw activations; norm fused into consumers)
    dim3 ngrid(GG, 8);
    const void* hptr = (const void*)B0;   // prev/conv-input; f32 for layer 0
    int habf = 0;
    ushort* Hout[2] = { H0, H1 };
    for (int i = 0; i < 2; ++i) {
        const ushort* Wc = (i == 0) ? convWt0 : convWt1;
        const ushort* Wf = (i == 0) ? fconvWt0 : fconvWt1;
        const float* bc  = conv_b  + (size_t)i * HH;
        const float* bfb = fconv_b + (size_t)i * HH;
        const float* nw  = norm_w  + (size_t)i * HH;
        const float* nb  = norm_b  + (size_t)i * HH;
        const float* nms = norm_ms + (size_t)i * HH;
        const float* fw  = fnorm_w + (size_t)i * HH;
        const float* fb  = fnorm_b + (size_t)i * HH;
        const float* fms = fnorm_ms+ (size_t)i * HH;
        // h-road conv -> bf16 messages (A raw, no norm)
        gemm_mfma<<<gemmGrid, 256, 0, stream>>>(hptr, nullptr, habf, Wc, nullptr, nullptr, Mr,
                                                NN, HH, HH, 2, nullptr, 0,
                                                nullptr, nullptr, nullptr, nullptr,
                                                nullptr, nullptr, nullptr, nullptr);
        gcn_gather<<<gatherGrid, 256, 0, stream>>>(Mr, row_ptr, deg_cnt, sorted_src,
                                                   dinv, bc, Ar);
        norm_stats<<<ngrid, 256, 0, stream>>>(Ar, S1p, S2p);
        norm_reduce<<<GG, 256, 0, stream>>>(S1p, S2p, nms, MMh, RSh);
        // f-road conv (A = normed(Ar) on the fly) -> bf16 messages
        gemm_mfma<<<gemmGrid, 256, 0, stream>>>(Ar, nullptr, 1, Wf, nullptr, nullptr, Mr,
                                                NN, HH, HH, 2, nullptr, 0,
                                                MMh, RSh, nw, nb,
                                                nullptr, nullptr, nullptr, nullptr);
        fgcn_gather<<<gatherGrid, 256, 0, stream>>>(Mr, fsrc, bfb, Br);
        norm_stats<<<ngrid, 256, 0, stream>>>(Br, S1p, S2p);
        norm_reduce<<<GG, 256, 0, stream>>>(S1p, S2p, fms, MMf, RSf);
        // gate + combine: A/A2 normed on stage AND in epilogue -> bf16 H_i
        gemm_mfma<<<gemmGrid, 256, 0, stream>>>(Ar, Br, 1, gateWt, gate_b, nullptr, Hout[i],
                                                NN, 2 * HH, HH, 1, hptr, habf,
                                                MMh, RSh, nw, nb,
                                                MMf, RSf, fw, fb);
        hptr = (const void*)Hout[i];
        habf = 1;
    }
    // all_x[0]=H0, all_x[1]=H1: gf = (sum H0 + 2*sum H1)/500
    pool_kernel<<<GG, 256, 0, stream>>>(H0, H1, (float*)d_out);
}